// Round 8
// baseline (451.559 us; speedup 1.0000x reference)
//
#include <hip/hip_runtime.h>
#include <hip/hip_fp16.h>

#define NN 100000
#define NE 1600000
#define N64 (NN * 64)
#define NB 196                        // buckets = dst>>9 (100000/512)
#define CAP 9216                      // bucket capacity (mean 8192, +11 sigma)

typedef __attribute__((ext_vector_type(8))) short bf16x8;
typedef __attribute__((ext_vector_type(4))) float fx4;

// ---- workspace layout (dword offsets) ----
#define W1D_OFF 0
#define W1S_OFF 448
#define W2D_OFF 896
#define W2S_OFF 4992
#define WB1F_OFF 9216                 // packed Wb frags layer1: 4096 dwords
#define WB2F_OFF 13312                // layer2: 4096 dwords
#define GCUR_OFF 17408                // bucket cursors [256]
#define A_OFF   32768
#define B_OFF   (A_OFF + N64)         // B stored as packed f16 pairs: 32 dwords/node
#define AGG_OFF (B_OFF + N64)
#define P1_OFF  (AGG_OFF + N64)       // int2[NB*CAP] bucket staging
#define SEDG_OFF (P1_OFF + 2 * NB * CAP)  // int2[NE] sorted edges

union FragU { int i[4]; bf16x8 f; };

static __device__ __forceinline__ unsigned pack_h2(float f0, float f1) {
    __half h0 = __float2half_rn(f0), h1 = __float2half_rn(f1);
    unsigned short u0 = *(unsigned short*)&h0, u1 = *(unsigned short*)&h1;
    return (unsigned)u0 | ((unsigned)u1 << 16);
}

// One prep kernel: zero bucket cursors, precombine Wa weights, build Wb MFMA frags.
__global__ __launch_bounds__(256) void prep_all(
    const float* __restrict__ W1a, const float* __restrict__ W1b,
    const float* __restrict__ W2a, const float* __restrict__ W2b,
    float* __restrict__ ws, int* __restrict__ gcur)
{
    int t = blockIdx.x * 256 + threadIdx.x;
    if (t < 256) gcur[t] = 0;
    if (t < 448) {
        float top = W1a[t], bot = W1a[448 + t];
        ws[W1D_OFF + t] = top - bot;
        ws[W1S_OFF + t] = bot;
    }
    if (t < 4096) {
        float top = W2a[t], bot = W2a[4096 + t];
        ws[W2D_OFF + t] = top - bot;
        ws[W2S_OFF + t] = bot;
    }
    // Wb fragments (hi/lo truncation split):
    // int4 index r = mat*512 + ks*256 + nt*64 + lane; lane gives k=(lane>>4)*8+j+32ks,
    // n=(lane&15)+16nt, j packed 2 per dword.
    if (t < 2048) {
        int layer = t >> 10;
        int r = t & 1023;
        int ks = (r >> 8) & 1, nt = (r >> 6) & 3, lane = r & 63, mat = r >> 9;
        const float* Wb = layer ? W2b : W1b;
        int* out = (int*)(ws + (layer ? WB2F_OFF : WB1F_OFF));
        int quad = lane >> 4, c = lane & 15, n = nt * 16 + c;
        unsigned dw[4];
#pragma unroll
        for (int d = 0; d < 4; ++d) {
            unsigned v[2];
#pragma unroll
            for (int e = 0; e < 2; ++e) {
                int k = quad * 8 + d * 2 + e + 32 * ks;
                float w = Wb[k * 64 + n];
                unsigned u = __float_as_uint(w);
                if (mat == 0) v[e] = u >> 16;                        // hi = trunc
                else {
                    float lo = w - __uint_as_float(u & 0xFFFF0000u); // exact residual
                    v[e] = __float_as_uint(lo) >> 16;
                }
            }
            dw[d] = (v[1] << 16) | v[0];
        }
        ((int4*)out)[r] = make_int4((int)dw[0], (int)dw[1], (int)dw[2], (int)dw[3]);
    }
}

// A[i] = x_i @ Wd + ba (fp32) ; B[i] = x_i @ Ws (packed f16) ; zero AGG row.
__global__ __launch_bounds__(256) void node_mlp1(
    const float* __restrict__ x, const float* __restrict__ Wd,
    const float* __restrict__ Ws, const float* __restrict__ ba,
    float* __restrict__ A, unsigned* __restrict__ Bu, float* __restrict__ agg)
{
    int i = blockIdx.x * 256 + threadIdx.x;
    if (i >= NN) return;
    float xv[7];
#pragma unroll
    for (int k = 0; k < 7; ++k) xv[k] = x[i * 7 + k];
    float4* pa = (float4*)(A + (size_t)i * 64);
    uint4*  pb = (uint4*)(Bu + (size_t)i * 32);
    float4* pz = (float4*)(agg + (size_t)i * 64);
#pragma unroll
    for (int q = 0; q < 16; ++q) pz[q] = make_float4(0.f, 0.f, 0.f, 0.f);
#pragma unroll
    for (int half = 0; half < 2; ++half) {
        float acc[32];
#pragma unroll
        for (int c = 0; c < 32; ++c) acc[c] = ba[half * 32 + c];
#pragma unroll
        for (int k = 0; k < 7; ++k)
#pragma unroll
            for (int c = 0; c < 32; ++c)
                acc[c] = fmaf(xv[k], Wd[k * 64 + half * 32 + c], acc[c]);
#pragma unroll
        for (int q = 0; q < 8; ++q)
            pa[half * 8 + q] = make_float4(acc[q*4], acc[q*4+1], acc[q*4+2], acc[q*4+3]);
#pragma unroll
        for (int c = 0; c < 32; ++c) acc[c] = 0.0f;
#pragma unroll
        for (int k = 0; k < 7; ++k)
#pragma unroll
            for (int c = 0; c < 32; ++c)
                acc[c] = fmaf(xv[k], Ws[k * 64 + half * 32 + c], acc[c]);
#pragma unroll
        for (int q = 0; q < 4; ++q)
            pb[half * 4 + q] = make_uint4(pack_h2(acc[q*8+0], acc[q*8+1]),
                                          pack_h2(acc[q*8+2], acc[q*8+3]),
                                          pack_h2(acc[q*8+4], acc[q*8+5]),
                                          pack_h2(acc[q*8+6], acc[q*8+7]));
    }
}

// A[i] = g_i @ Wd + ba2 (fp32) ; B[i] = g_i @ Ws (packed f16) ; zero g row.
__global__ __launch_bounds__(256) void node_mlp2(
    float* __restrict__ g, const float* __restrict__ Wd,
    const float* __restrict__ Ws, const float* __restrict__ ba2,
    float* __restrict__ A, unsigned* __restrict__ Bu)
{
    int i = blockIdx.x * 256 + threadIdx.x;
    if (i >= NN) return;
    float gv[64];
    float4* pg = (float4*)(g + (size_t)i * 64);
#pragma unroll
    for (int q = 0; q < 16; ++q) {
        float4 v = pg[q];
        gv[q*4+0] = v.x; gv[q*4+1] = v.y; gv[q*4+2] = v.z; gv[q*4+3] = v.w;
    }
#pragma unroll
    for (int q = 0; q < 16; ++q) pg[q] = make_float4(0.f, 0.f, 0.f, 0.f);
    float4* pa = (float4*)(A + (size_t)i * 64);
    uint4*  pb = (uint4*)(Bu + (size_t)i * 32);
#pragma unroll
    for (int half = 0; half < 2; ++half) {
        float acc[32];
#pragma unroll
        for (int c = 0; c < 32; ++c) acc[c] = ba2[half * 32 + c];
#pragma unroll
        for (int j = 0; j < 64; ++j)
#pragma unroll
            for (int c = 0; c < 32; ++c)
                acc[c] = fmaf(gv[j], Wd[j * 64 + half * 32 + c], acc[c]);
#pragma unroll
        for (int q = 0; q < 8; ++q)
            pa[half * 8 + q] = make_float4(acc[q*4], acc[q*4+1], acc[q*4+2], acc[q*4+3]);
#pragma unroll
        for (int c = 0; c < 32; ++c) acc[c] = 0.0f;
#pragma unroll
        for (int j = 0; j < 64; ++j)
#pragma unroll
            for (int c = 0; c < 32; ++c)
                acc[c] = fmaf(gv[j], Ws[j * 64 + half * 32 + c], acc[c]);
#pragma unroll
        for (int q = 0; q < 4; ++q)
            pb[half * 4 + q] = make_uint4(pack_h2(acc[q*8+0], acc[q*8+1]),
                                          pack_h2(acc[q*8+2], acc[q*8+3]),
                                          pack_h2(acc[q*8+4], acc[q*8+5]),
                                          pack_h2(acc[q*8+6], acc[q*8+7]));
    }
}

// ---- two-pass edge sort by dst ----
__global__ __launch_bounds__(256) void k_bucket(
    const int* __restrict__ src, const int* __restrict__ dst,
    int* __restrict__ gcur, int2* __restrict__ p1)
{
    __shared__ int cnt[NB];
    __shared__ int cur[NB];
    const int t = threadIdx.x;
    const int e0 = (blockIdx.x * 256 + t) * 8;
    const bool ok = (e0 < NE);                   // NE % 8 == 0
    if (t < NB) cnt[t] = 0;
    int ss[8], dd[8], bk[8];
    if (ok) {
        int4 d0 = ((const int4*)(dst + e0))[0];
        int4 d1 = ((const int4*)(dst + e0))[1];
        int4 s0 = ((const int4*)(src + e0))[0];
        int4 s1 = ((const int4*)(src + e0))[1];
        dd[0]=d0.x; dd[1]=d0.y; dd[2]=d0.z; dd[3]=d0.w;
        dd[4]=d1.x; dd[5]=d1.y; dd[6]=d1.z; dd[7]=d1.w;
        ss[0]=s0.x; ss[1]=s0.y; ss[2]=s0.z; ss[3]=s0.w;
        ss[4]=s1.x; ss[5]=s1.y; ss[6]=s1.z; ss[7]=s1.w;
    }
    __syncthreads();
    if (ok) {
#pragma unroll
        for (int j = 0; j < 8; ++j) { bk[j] = dd[j] >> 9; atomicAdd(&cnt[bk[j]], 1); }
    }
    __syncthreads();
    if (t < NB) cur[t] = atomicAdd(&gcur[t], cnt[t]);   // reserve block's ranges
    __syncthreads();
    if (ok) {
#pragma unroll
        for (int j = 0; j < 8; ++j) {
            int pos = atomicAdd(&cur[bk[j]], 1);
            p1[(size_t)bk[j] * CAP + pos] = make_int2(ss[j], dd[j]);
        }
    }
}

__global__ __launch_bounds__(256) void k_sortbkt(
    const int2* __restrict__ p1, const int* __restrict__ gcnt,
    int2* __restrict__ sedge)
{
    __shared__ int sz[256];
    __shared__ int cnt[512];
    __shared__ int cur[512];
    __shared__ int pairb[256];
    const int b = blockIdx.x, t = threadIdx.x;
    sz[t] = (t < NB) ? gcnt[t] : 0;
    cnt[t] = 0; cnt[t + 256] = 0;
    __syncthreads();
#pragma unroll
    for (int off = 1; off < 256; off <<= 1) {       // inclusive scan of bucket sizes
        int u = (t >= off) ? sz[t - off] : 0;
        __syncthreads();
        sz[t] += u;
        __syncthreads();
    }
    const int myBase = (b == 0) ? 0 : sz[b - 1];
    const int mySize = gcnt[b];
    const int2* bp = p1 + (size_t)b * CAP;
    for (int i = t; i < mySize; i += 256) atomicAdd(&cnt[bp[i].y & 511], 1);
    __syncthreads();
    pairb[t] = cnt[2 * t] + cnt[2 * t + 1];
    __syncthreads();
#pragma unroll
    for (int off = 1; off < 256; off <<= 1) {       // scan pair-sums
        int u = (t >= off) ? pairb[t - off] : 0;
        __syncthreads();
        pairb[t] += u;
        __syncthreads();
    }
    int ex = (t == 0) ? 0 : pairb[t - 1];
    cur[2 * t] = ex;
    cur[2 * t + 1] = ex + cnt[2 * t];
    __syncthreads();
    for (int i = t; i < mySize; i += 256) {
        int2 e = bp[i];
        int pos = atomicAdd(&cur[e.y & 511], 1);
        sedge[(size_t)myBase + pos] = e;
    }
}

// MFMA edge layer: wave = 32 edges (2 mt tiles). A gathered fp32 (dst-local),
// B gathered packed f16 (random: half the bytes & requests of fp32).
// All gathers front-loaded; t=relu(a+b) split to bf16 hi/lo in-register;
// 3-pass split MFMA; epilogue 16-edge LDS chunks + segmented atomicMax.
__global__ __launch_bounds__(256, 3) void edge_layer_mfma(
    const float* __restrict__ A, const unsigned* __restrict__ Bu,
    const int2* __restrict__ se,
    const int* __restrict__ wbf, const float* __restrict__ bb,
    unsigned int* __restrict__ agg)
{
    __shared__ int lds[4][1024];           // per wave: 16-edge epilogue chunk
    const int tid = threadIdx.x;
    const int wv = tid >> 6, lane = tid & 63;
    int* chunk = lds[wv];
    const int quad = lane >> 4, c15 = lane & 15;
    const int base = (blockIdx.x * 4 + wv) * 32;

    int2 ed  = se[base + (lane & 31)];     // this wave's 32 edges (dup in hi half)
    int2 eb0 = se[base + c15];             // fragment-row edge, mt=0 (quad-uniform)
    int2 eb1 = se[base + 16 + c15];        // mt=1

    const float*    pa0 = A  + (size_t)eb0.y * 64 + quad * 8;
    const unsigned* pb0 = Bu + (size_t)eb0.x * 32 + quad * 4;
    const float*    pa1 = A  + (size_t)eb1.y * 64 + quad * 8;
    const unsigned* pb1 = Bu + (size_t)eb1.x * 32 + quad * 4;

    // front-load ALL gathers: A 2x float4 per (mt,ks), B 1x uint4 per (mt,ks)
    float4 ga[2][2][2];
    uint4  gb[2][2];
#pragma unroll
    for (int ks = 0; ks < 2; ++ks) {
#pragma unroll
        for (int h = 0; h < 2; ++h) {
            ga[0][ks][h] = ((const float4*)(pa0 + ks * 32))[h];
            ga[1][ks][h] = ((const float4*)(pa1 + ks * 32))[h];
        }
        gb[0][ks] = ((const uint4*)(pb0 + ks * 16))[0];
        gb[1][ks] = ((const uint4*)(pb1 + ks * 16))[0];
    }

    // t = relu(a + f32(b_f16)), pack bf16 hi/lo: frags [mt][ks]
    bf16x8 fah[2][2], fal[2][2];
#pragma unroll
    for (int mt = 0; mt < 2; ++mt)
#pragma unroll
        for (int ks = 0; ks < 2; ++ks) {
            unsigned bu[4] = { gb[mt][ks].x, gb[mt][ks].y, gb[mt][ks].z, gb[mt][ks].w };
            float t[8];
#pragma unroll
            for (int h = 0; h < 2; ++h) {
                float4 a = ga[mt][ks][h];
                float2 b0 = __half22float2(*(const __half2*)&bu[h * 2 + 0]);
                float2 b1 = __half22float2(*(const __half2*)&bu[h * 2 + 1]);
                t[h*4+0] = fmaxf(a.x + b0.x, 0.f);
                t[h*4+1] = fmaxf(a.y + b0.y, 0.f);
                t[h*4+2] = fmaxf(a.z + b1.x, 0.f);
                t[h*4+3] = fmaxf(a.w + b1.y, 0.f);
            }
            FragU uh, ul;
#pragma unroll
            for (int d2 = 0; d2 < 4; ++d2) {
                unsigned u0 = __float_as_uint(t[2 * d2]);
                unsigned u1 = __float_as_uint(t[2 * d2 + 1]);
                uh.i[d2] = (int)((u1 & 0xFFFF0000u) | (u0 >> 16));
                float l0 = t[2 * d2]     - __uint_as_float(u0 & 0xFFFF0000u);
                float l1 = t[2 * d2 + 1] - __uint_as_float(u1 & 0xFFFF0000u);
                ul.i[d2] = (int)((__float_as_uint(l1) & 0xFFFF0000u) |
                                 (__float_as_uint(l0) >> 16));
            }
            fah[mt][ks] = uh.f; fal[mt][ks] = ul.f;
        }

    fx4 acc[2][4];
#pragma unroll
    for (int mt = 0; mt < 2; ++mt)
#pragma unroll
        for (int nt = 0; nt < 4; ++nt)
            acc[mt][nt] = (fx4){0.f, 0.f, 0.f, 0.f};

#pragma unroll
    for (int ks = 0; ks < 2; ++ks) {
        bf16x8 wh[4], wl[4];
#pragma unroll
        for (int nt = 0; nt < 4; ++nt) {
            int4 v = ((const int4*)wbf)[(ks * 4 + nt) * 64 + lane];          // hi
            FragU u; u.i[0] = v.x; u.i[1] = v.y; u.i[2] = v.z; u.i[3] = v.w;
            wh[nt] = u.f;
            int4 v2 = ((const int4*)wbf)[((2 + ks) * 4 + nt) * 64 + lane];   // lo
            FragU u2; u2.i[0] = v2.x; u2.i[1] = v2.y; u2.i[2] = v2.z; u2.i[3] = v2.w;
            wl[nt] = u2.f;
        }
#pragma unroll
        for (int mt = 0; mt < 2; ++mt)
#pragma unroll
            for (int nt = 0; nt < 4; ++nt) {
                acc[mt][nt] = __builtin_amdgcn_mfma_f32_16x16x32_bf16(fah[mt][ks], wh[nt], acc[mt][nt], 0, 0, 0);
                acc[mt][nt] = __builtin_amdgcn_mfma_f32_16x16x32_bf16(fah[mt][ks], wl[nt], acc[mt][nt], 0, 0, 0);
                acc[mt][nt] = __builtin_amdgcn_mfma_f32_16x16x32_bf16(fal[mt][ks], wh[nt], acc[mt][nt], 0, 0, 0);
            }
    }

    // epilogue: bias+relu, 16-edge LDS chunks (2-way-max bank swizzle), segmented max
    float bbv[4];
#pragma unroll
    for (int nt = 0; nt < 4; ++nt) bbv[nt] = bb[nt * 16 + c15];

    int dprev = __builtin_amdgcn_readlane(ed.y, 0);
    float run = 0.f;
#pragma unroll
    for (int mt = 0; mt < 2; ++mt) {
#pragma unroll
        for (int nt = 0; nt < 4; ++nt)
#pragma unroll
            for (int r = 0; r < 4; ++r) {
                int ee = mt * 16 + quad * 4 + r;
                int ch = nt * 16 + c15;
                float h = fmaxf(acc[mt][nt][r] + bbv[nt], 0.f);
                chunk[(ee & 15) * 64 + ((ch + 4 * ee) & 63)] = __float_as_int(h);
            }
#pragma unroll
        for (int i = 0; i < 16; ++i) {
            int ee = mt * 16 + i;
            float v = __int_as_float(chunk[i * 64 + ((lane + 4 * ee) & 63)]);
            int dd = __builtin_amdgcn_readlane(ed.y, ee);
            if (dd != dprev) {
                atomicMax(&agg[(size_t)dprev * 64 + lane], __float_as_uint(run));
                run = 0.f; dprev = dd;
            }
            run = fmaxf(run, v);
        }
    }
    atomicMax(&agg[(size_t)dprev * 64 + lane], __float_as_uint(run));
}

// out[i] = h2[i,:] @ Wl + bl
__global__ __launch_bounds__(256) void final_linear(
    const float* __restrict__ h2, const float* __restrict__ Wl,
    const float* __restrict__ bl, float* __restrict__ out)
{
    int i = blockIdx.x * 256 + threadIdx.x;
    if (i >= NN) return;
    const float4* row = (const float4*)(h2 + (size_t)i * 64);
    float acc = bl[0];
#pragma unroll
    for (int q = 0; q < 16; ++q) {
        float4 v = row[q];
        acc = fmaf(v.x, Wl[q * 4 + 0], acc);
        acc = fmaf(v.y, Wl[q * 4 + 1], acc);
        acc = fmaf(v.z, Wl[q * 4 + 2], acc);
        acc = fmaf(v.w, Wl[q * 4 + 3], acc);
    }
    out[i] = acc;
}

extern "C" void kernel_launch(void* const* d_in, const int* in_sizes, int n_in,
                              void* d_out, int out_size, void* d_ws, size_t ws_size,
                              hipStream_t stream)
{
    const float* x   = (const float*)d_in[0];
    const int*   ei  = (const int*)d_in[1];
    const float* W1a = (const float*)d_in[2];
    const float* b1a = (const float*)d_in[3];
    const float* W1b = (const float*)d_in[4];
    const float* b1b = (const float*)d_in[5];
    const float* W2a = (const float*)d_in[6];
    const float* b2a = (const float*)d_in[7];
    const float* W2b = (const float*)d_in[8];
    const float* b2b = (const float*)d_in[9];
    const float* Wl  = (const float*)d_in[10];
    const float* bl  = (const float*)d_in[11];

    const int* src = ei;
    const int* dst = ei + NE;

    float* ws = (float*)d_ws;
    float* A        = ws + A_OFF;
    unsigned* Bu    = (unsigned*)(ws + B_OFF);
    unsigned int* AGG = (unsigned int*)(ws + AGG_OFF);
    int*  gcur  = (int*)(ws + GCUR_OFF);
    int2* p1    = (int2*)(ws + P1_OFF);
    int2* sedge = (int2*)(ws + SEDG_OFF);

    prep_all<<<16, 256, 0, stream>>>(W1a, W1b, W2a, W2b, ws, gcur);
    node_mlp1<<<391, 256, 0, stream>>>(x, ws + W1D_OFF, ws + W1S_OFF, b1a, A, Bu, (float*)AGG);

    k_bucket <<<782, 256, 0, stream>>>(src, dst, gcur, p1);
    k_sortbkt<<<NB, 256, 0, stream>>>(p1, gcur, sedge);

    edge_layer_mfma<<<NE / 128, 256, 0, stream>>>(A, Bu, sedge,
                                                  (const int*)(ws + WB1F_OFF), b1b, AGG);

    node_mlp2<<<391, 256, 0, stream>>>((float*)AGG, ws + W2D_OFF, ws + W2S_OFF, b2a, A, Bu);

    edge_layer_mfma<<<NE / 128, 256, 0, stream>>>(A, Bu, sedge,
                                                  (const int*)(ws + WB2F_OFF), b2b, AGG);

    final_linear<<<391, 256, 0, stream>>>((const float*)AGG, Wl, bl, (float*)d_out);
}

// Round 10
// 399.616 us; speedup vs baseline: 1.1300x; 1.1300x over previous
//
#include <hip/hip_runtime.h>
#include <hip/hip_fp16.h>

#define NN 100000
#define NE 1600000
#define N64 (NN * 64)
#define NB 196                        // buckets = dst>>9 (100000/512)
#define CAP 9216                      // bucket capacity (mean 8192, +11 sigma)

typedef __attribute__((ext_vector_type(8))) short bf16x8;
typedef __attribute__((ext_vector_type(4))) float fx4;

// ---- workspace layout (dword offsets) ----
#define W1D_OFF 0
#define W1S_OFF 448
#define W2D_OFF 896
#define W2S_OFF 4992
#define WB1F_OFF 9216                 // packed Wb frags layer1: 4096 dwords
#define WB2F_OFF 13312                // layer2: 4096 dwords
#define GCUR_OFF 17408                // bucket cursors [256]
#define A_OFF   32768
#define B_OFF   (A_OFF + N64)         // B stored as packed f16 pairs: 32 dwords/node
#define AGG_OFF (B_OFF + N64)
#define P1_OFF  (AGG_OFF + N64)       // int2[NB*CAP] bucket staging
#define SEDG_OFF (P1_OFF + 2 * NB * CAP)  // int2[NE] sorted edges

union FragU { int i[4]; bf16x8 f; };

static __device__ __forceinline__ unsigned pack_h2(float f0, float f1) {
    __half h0 = __float2half_rn(f0), h1 = __float2half_rn(f1);
    unsigned short u0 = *(unsigned short*)&h0, u1 = *(unsigned short*)&h1;
    return (unsigned)u0 | ((unsigned)u1 << 16);
}

// One prep kernel: zero bucket cursors, precombine Wa weights, build Wb MFMA frags.
__global__ __launch_bounds__(256) void prep_all(
    const float* __restrict__ W1a, const float* __restrict__ W1b,
    const float* __restrict__ W2a, const float* __restrict__ W2b,
    float* __restrict__ ws, int* __restrict__ gcur)
{
    int t = blockIdx.x * 256 + threadIdx.x;
    if (t < 256) gcur[t] = 0;
    if (t < 448) {
        float top = W1a[t], bot = W1a[448 + t];
        ws[W1D_OFF + t] = top - bot;
        ws[W1S_OFF + t] = bot;
    }
    if (t < 4096) {
        float top = W2a[t], bot = W2a[4096 + t];
        ws[W2D_OFF + t] = top - bot;
        ws[W2S_OFF + t] = bot;
    }
    // Wb fragments (hi/lo truncation split):
    // int4 index r = mat*512 + ks*256 + nt*64 + lane; lane gives k=(lane>>4)*8+j+32ks,
    // n=(lane&15)+16nt, j packed 2 per dword.
    if (t < 2048) {
        int layer = t >> 10;
        int r = t & 1023;
        int ks = (r >> 8) & 1, nt = (r >> 6) & 3, lane = r & 63, mat = r >> 9;
        const float* Wb = layer ? W2b : W1b;
        int* out = (int*)(ws + (layer ? WB2F_OFF : WB1F_OFF));
        int quad = lane >> 4, c = lane & 15, n = nt * 16 + c;
        unsigned dw[4];
#pragma unroll
        for (int d = 0; d < 4; ++d) {
            unsigned v[2];
#pragma unroll
            for (int e = 0; e < 2; ++e) {
                int k = quad * 8 + d * 2 + e + 32 * ks;
                float w = Wb[k * 64 + n];
                unsigned u = __float_as_uint(w);
                if (mat == 0) v[e] = u >> 16;                        // hi = trunc
                else {
                    float lo = w - __uint_as_float(u & 0xFFFF0000u); // exact residual
                    v[e] = __float_as_uint(lo) >> 16;
                }
            }
            dw[d] = (v[1] << 16) | v[0];
        }
        ((int4*)out)[r] = make_int4((int)dw[0], (int)dw[1], (int)dw[2], (int)dw[3]);
    }
}

// Zero a float4-aligned region (replaces mid-pipeline hipMemsetAsync: a kernel
// node gets correct stream-order deps in graph capture; the memset node did not
// -- R9's replay-only divergence).
__global__ __launch_bounds__(256) void k_zero(float4* __restrict__ p)
{
    p[(size_t)blockIdx.x * 256 + threadIdx.x] = make_float4(0.f, 0.f, 0.f, 0.f);
}

// Node MLP layer 1, quarter-split: q = blockIdx&3 selects 16 output channels
// (block-uniform -> weight reads stay scalar). A quarter fp32 + Bu quarter f16;
// also zeroes its AGG quarter (mlp1 never reads agg -> no race).
__global__ __launch_bounds__(256) void node_mlp1(
    const float* __restrict__ x, const float* __restrict__ Wd,
    const float* __restrict__ Ws, const float* __restrict__ ba,
    float* __restrict__ A, unsigned* __restrict__ Bu, float* __restrict__ agg)
{
    const int q = blockIdx.x & 3;
    const int i = (blockIdx.x >> 2) * 256 + threadIdx.x;
    if (i >= NN) return;
    float xv[7];
#pragma unroll
    for (int k = 0; k < 7; ++k) xv[k] = x[i * 7 + k];

    float4* pa = (float4*)(A + (size_t)i * 64 + q * 16);
    float4* pz = (float4*)(agg + (size_t)i * 64 + q * 16);
    uint4*  pb = (uint4*)(Bu + (size_t)i * 32 + q * 8);
#pragma unroll
    for (int f = 0; f < 4; ++f) pz[f] = make_float4(0.f, 0.f, 0.f, 0.f);

    float acc[16];
#pragma unroll
    for (int c = 0; c < 16; ++c) acc[c] = ba[q * 16 + c];
#pragma unroll
    for (int k = 0; k < 7; ++k)
#pragma unroll
        for (int c = 0; c < 16; ++c)
            acc[c] = fmaf(xv[k], Wd[k * 64 + q * 16 + c], acc[c]);
#pragma unroll
    for (int f = 0; f < 4; ++f)
        pa[f] = make_float4(acc[f*4], acc[f*4+1], acc[f*4+2], acc[f*4+3]);

#pragma unroll
    for (int c = 0; c < 16; ++c) acc[c] = 0.0f;
#pragma unroll
    for (int k = 0; k < 7; ++k)
#pragma unroll
        for (int c = 0; c < 16; ++c)
            acc[c] = fmaf(xv[k], Ws[k * 64 + q * 16 + c], acc[c]);
    pb[0] = make_uint4(pack_h2(acc[0], acc[1]),  pack_h2(acc[2], acc[3]),
                       pack_h2(acc[4], acc[5]),  pack_h2(acc[6], acc[7]));
    pb[1] = make_uint4(pack_h2(acc[8], acc[9]),  pack_h2(acc[10], acc[11]),
                       pack_h2(acc[12], acc[13]), pack_h2(acc[14], acc[15]));
}

// Node MLP layer 2, quarter-split (reads full g row; does NOT zero g --
// g is re-zeroed by k_zero after this kernel to avoid a cross-block race).
__global__ __launch_bounds__(256) void node_mlp2(
    const float* __restrict__ g, const float* __restrict__ Wd,
    const float* __restrict__ Ws, const float* __restrict__ ba2,
    float* __restrict__ A, unsigned* __restrict__ Bu)
{
    const int q = blockIdx.x & 3;
    const int i = (blockIdx.x >> 2) * 256 + threadIdx.x;
    if (i >= NN) return;
    float gv[64];
    const float4* pg = (const float4*)(g + (size_t)i * 64);
#pragma unroll
    for (int r = 0; r < 16; ++r) {
        float4 v = pg[r];
        gv[r*4+0] = v.x; gv[r*4+1] = v.y; gv[r*4+2] = v.z; gv[r*4+3] = v.w;
    }
    float4* pa = (float4*)(A + (size_t)i * 64 + q * 16);
    uint4*  pb = (uint4*)(Bu + (size_t)i * 32 + q * 8);

    float acc[16];
#pragma unroll
    for (int c = 0; c < 16; ++c) acc[c] = ba2[q * 16 + c];
#pragma unroll
    for (int j = 0; j < 64; ++j)
#pragma unroll
        for (int c = 0; c < 16; ++c)
            acc[c] = fmaf(gv[j], Wd[j * 64 + q * 16 + c], acc[c]);
#pragma unroll
    for (int f = 0; f < 4; ++f)
        pa[f] = make_float4(acc[f*4], acc[f*4+1], acc[f*4+2], acc[f*4+3]);

#pragma unroll
    for (int c = 0; c < 16; ++c) acc[c] = 0.0f;
#pragma unroll
    for (int j = 0; j < 64; ++j)
#pragma unroll
        for (int c = 0; c < 16; ++c)
            acc[c] = fmaf(gv[j], Ws[j * 64 + q * 16 + c], acc[c]);
    pb[0] = make_uint4(pack_h2(acc[0], acc[1]),  pack_h2(acc[2], acc[3]),
                       pack_h2(acc[4], acc[5]),  pack_h2(acc[6], acc[7]));
    pb[1] = make_uint4(pack_h2(acc[8], acc[9]),  pack_h2(acc[10], acc[11]),
                       pack_h2(acc[12], acc[13]), pack_h2(acc[14], acc[15]));
}

// ---- two-pass edge sort by dst ----
__global__ __launch_bounds__(256) void k_bucket(
    const int* __restrict__ src, const int* __restrict__ dst,
    int* __restrict__ gcur, int2* __restrict__ p1)
{
    __shared__ int cnt[NB];
    __shared__ int cur[NB];
    const int t = threadIdx.x;
    const int e0 = (blockIdx.x * 256 + t) * 8;
    const bool ok = (e0 < NE);                   // NE % 8 == 0
    if (t < NB) cnt[t] = 0;
    int ss[8], dd[8], bk[8];
    if (ok) {
        int4 d0 = ((const int4*)(dst + e0))[0];
        int4 d1 = ((const int4*)(dst + e0))[1];
        int4 s0 = ((const int4*)(src + e0))[0];
        int4 s1 = ((const int4*)(src + e0))[1];
        dd[0]=d0.x; dd[1]=d0.y; dd[2]=d0.z; dd[3]=d0.w;
        dd[4]=d1.x; dd[5]=d1.y; dd[6]=d1.z; dd[7]=d1.w;
        ss[0]=s0.x; ss[1]=s0.y; ss[2]=s0.z; ss[3]=s0.w;
        ss[4]=s1.x; ss[5]=s1.y; ss[6]=s1.z; ss[7]=s1.w;
    }
    __syncthreads();
    if (ok) {
#pragma unroll
        for (int j = 0; j < 8; ++j) { bk[j] = dd[j] >> 9; atomicAdd(&cnt[bk[j]], 1); }
    }
    __syncthreads();
    if (t < NB) cur[t] = atomicAdd(&gcur[t], cnt[t]);   // reserve block's ranges
    __syncthreads();
    if (ok) {
#pragma unroll
        for (int j = 0; j < 8; ++j) {
            int pos = atomicAdd(&cur[bk[j]], 1);
            p1[(size_t)bk[j] * CAP + pos] = make_int2(ss[j], dd[j]);
        }
    }
}

__global__ __launch_bounds__(256) void k_sortbkt(
    const int2* __restrict__ p1, const int* __restrict__ gcnt,
    int2* __restrict__ sedge)
{
    __shared__ int sz[256];
    __shared__ int cnt[512];
    __shared__ int cur[512];
    __shared__ int pairb[256];
    const int b = blockIdx.x, t = threadIdx.x;
    sz[t] = (t < NB) ? gcnt[t] : 0;
    cnt[t] = 0; cnt[t + 256] = 0;
    __syncthreads();
#pragma unroll
    for (int off = 1; off < 256; off <<= 1) {       // inclusive scan of bucket sizes
        int u = (t >= off) ? sz[t - off] : 0;
        __syncthreads();
        sz[t] += u;
        __syncthreads();
    }
    const int myBase = (b == 0) ? 0 : sz[b - 1];
    const int mySize = gcnt[b];
    const int2* bp = p1 + (size_t)b * CAP;
    for (int i = t; i < mySize; i += 256) atomicAdd(&cnt[bp[i].y & 511], 1);
    __syncthreads();
    pairb[t] = cnt[2 * t] + cnt[2 * t + 1];
    __syncthreads();
#pragma unroll
    for (int off = 1; off < 256; off <<= 1) {       // scan pair-sums
        int u = (t >= off) ? pairb[t - off] : 0;
        __syncthreads();
        pairb[t] += u;
        __syncthreads();
    }
    int ex = (t == 0) ? 0 : pairb[t - 1];
    cur[2 * t] = ex;
    cur[2 * t + 1] = ex + cnt[2 * t];
    __syncthreads();
    for (int i = t; i < mySize; i += 256) {
        int2 e = bp[i];
        int pos = atomicAdd(&cur[e.y & 511], 1);
        sedge[(size_t)myBase + pos] = e;
    }
}

// MFMA edge layer: wave = 32 edges (2 mt tiles). A gathered fp32 (dst-local),
// B gathered packed f16 (random: half the bytes & requests of fp32).
// All gathers front-loaded; t=relu(a+b) split to bf16 hi/lo in-register;
// 3-pass split MFMA; epilogue 16-edge LDS chunks + segmented atomicMax.
__global__ __launch_bounds__(256, 3) void edge_layer_mfma(
    const float* __restrict__ A, const unsigned* __restrict__ Bu,
    const int2* __restrict__ se,
    const int* __restrict__ wbf, const float* __restrict__ bb,
    unsigned int* __restrict__ agg)
{
    __shared__ int lds[4][1024];           // per wave: 16-edge epilogue chunk
    const int tid = threadIdx.x;
    const int wv = tid >> 6, lane = tid & 63;
    int* chunk = lds[wv];
    const int quad = lane >> 4, c15 = lane & 15;
    const int base = (blockIdx.x * 4 + wv) * 32;

    int2 ed  = se[base + (lane & 31)];     // this wave's 32 edges (dup in hi half)
    int2 eb0 = se[base + c15];             // fragment-row edge, mt=0 (quad-uniform)
    int2 eb1 = se[base + 16 + c15];        // mt=1

    const float*    pa0 = A  + (size_t)eb0.y * 64 + quad * 8;
    const unsigned* pb0 = Bu + (size_t)eb0.x * 32 + quad * 4;
    const float*    pa1 = A  + (size_t)eb1.y * 64 + quad * 8;
    const unsigned* pb1 = Bu + (size_t)eb1.x * 32 + quad * 4;

    // front-load ALL gathers: A 2x float4 per (mt,ks), B 1x uint4 per (mt,ks)
    float4 ga[2][2][2];
    uint4  gb[2][2];
#pragma unroll
    for (int ks = 0; ks < 2; ++ks) {
#pragma unroll
        for (int h = 0; h < 2; ++h) {
            ga[0][ks][h] = ((const float4*)(pa0 + ks * 32))[h];
            ga[1][ks][h] = ((const float4*)(pa1 + ks * 32))[h];
        }
        gb[0][ks] = ((const uint4*)(pb0 + ks * 16))[0];
        gb[1][ks] = ((const uint4*)(pb1 + ks * 16))[0];
    }

    // t = relu(a + f32(b_f16)), pack bf16 hi/lo: frags [mt][ks]
    bf16x8 fah[2][2], fal[2][2];
#pragma unroll
    for (int mt = 0; mt < 2; ++mt)
#pragma unroll
        for (int ks = 0; ks < 2; ++ks) {
            unsigned bu[4] = { gb[mt][ks].x, gb[mt][ks].y, gb[mt][ks].z, gb[mt][ks].w };
            float t[8];
#pragma unroll
            for (int h = 0; h < 2; ++h) {
                float4 a = ga[mt][ks][h];
                float2 b0 = __half22float2(*(const __half2*)&bu[h * 2 + 0]);
                float2 b1 = __half22float2(*(const __half2*)&bu[h * 2 + 1]);
                t[h*4+0] = fmaxf(a.x + b0.x, 0.f);
                t[h*4+1] = fmaxf(a.y + b0.y, 0.f);
                t[h*4+2] = fmaxf(a.z + b1.x, 0.f);
                t[h*4+3] = fmaxf(a.w + b1.y, 0.f);
            }
            FragU uh, ul;
#pragma unroll
            for (int d2 = 0; d2 < 4; ++d2) {
                unsigned u0 = __float_as_uint(t[2 * d2]);
                unsigned u1 = __float_as_uint(t[2 * d2 + 1]);
                uh.i[d2] = (int)((u1 & 0xFFFF0000u) | (u0 >> 16));
                float l0 = t[2 * d2]     - __uint_as_float(u0 & 0xFFFF0000u);
                float l1 = t[2 * d2 + 1] - __uint_as_float(u1 & 0xFFFF0000u);
                ul.i[d2] = (int)((__float_as_uint(l1) & 0xFFFF0000u) |
                                 (__float_as_uint(l0) >> 16));
            }
            fah[mt][ks] = uh.f; fal[mt][ks] = ul.f;
        }

    fx4 acc[2][4];
#pragma unroll
    for (int mt = 0; mt < 2; ++mt)
#pragma unroll
        for (int nt = 0; nt < 4; ++nt)
            acc[mt][nt] = (fx4){0.f, 0.f, 0.f, 0.f};

#pragma unroll
    for (int ks = 0; ks < 2; ++ks) {
        bf16x8 wh[4], wl[4];
#pragma unroll
        for (int nt = 0; nt < 4; ++nt) {
            int4 v = ((const int4*)wbf)[(ks * 4 + nt) * 64 + lane];          // hi
            FragU u; u.i[0] = v.x; u.i[1] = v.y; u.i[2] = v.z; u.i[3] = v.w;
            wh[nt] = u.f;
            int4 v2 = ((const int4*)wbf)[((2 + ks) * 4 + nt) * 64 + lane];   // lo
            FragU u2; u2.i[0] = v2.x; u2.i[1] = v2.y; u2.i[2] = v2.z; u2.i[3] = v2.w;
            wl[nt] = u2.f;
        }
#pragma unroll
        for (int mt = 0; mt < 2; ++mt)
#pragma unroll
            for (int nt = 0; nt < 4; ++nt) {
                acc[mt][nt] = __builtin_amdgcn_mfma_f32_16x16x32_bf16(fah[mt][ks], wh[nt], acc[mt][nt], 0, 0, 0);
                acc[mt][nt] = __builtin_amdgcn_mfma_f32_16x16x32_bf16(fah[mt][ks], wl[nt], acc[mt][nt], 0, 0, 0);
                acc[mt][nt] = __builtin_amdgcn_mfma_f32_16x16x32_bf16(fal[mt][ks], wh[nt], acc[mt][nt], 0, 0, 0);
            }
    }

    // epilogue: bias+relu, 16-edge LDS chunks (2-way-max bank swizzle), segmented max
    float bbv[4];
#pragma unroll
    for (int nt = 0; nt < 4; ++nt) bbv[nt] = bb[nt * 16 + c15];

    int dprev = __builtin_amdgcn_readlane(ed.y, 0);
    float run = 0.f;
#pragma unroll
    for (int mt = 0; mt < 2; ++mt) {
#pragma unroll
        for (int nt = 0; nt < 4; ++nt)
#pragma unroll
            for (int r = 0; r < 4; ++r) {
                int ee = mt * 16 + quad * 4 + r;
                int ch = nt * 16 + c15;
                float h = fmaxf(acc[mt][nt][r] + bbv[nt], 0.f);
                chunk[(ee & 15) * 64 + ((ch + 4 * ee) & 63)] = __float_as_int(h);
            }
#pragma unroll
        for (int i = 0; i < 16; ++i) {
            int ee = mt * 16 + i;
            float v = __int_as_float(chunk[i * 64 + ((lane + 4 * ee) & 63)]);
            int dd = __builtin_amdgcn_readlane(ed.y, ee);
            if (dd != dprev) {
                atomicMax(&agg[(size_t)dprev * 64 + lane], __float_as_uint(run));
                run = 0.f; dprev = dd;
            }
            run = fmaxf(run, v);
        }
    }
    atomicMax(&agg[(size_t)dprev * 64 + lane], __float_as_uint(run));
}

// out[i] = h2[i,:] @ Wl + bl
__global__ __launch_bounds__(256) void final_linear(
    const float* __restrict__ h2, const float* __restrict__ Wl,
    const float* __restrict__ bl, float* __restrict__ out)
{
    int i = blockIdx.x * 256 + threadIdx.x;
    if (i >= NN) return;
    const float4* row = (const float4*)(h2 + (size_t)i * 64);
    float acc = bl[0];
#pragma unroll
    for (int q = 0; q < 16; ++q) {
        float4 v = row[q];
        acc = fmaf(v.x, Wl[q * 4 + 0], acc);
        acc = fmaf(v.y, Wl[q * 4 + 1], acc);
        acc = fmaf(v.z, Wl[q * 4 + 2], acc);
        acc = fmaf(v.w, Wl[q * 4 + 3], acc);
    }
    out[i] = acc;
}

extern "C" void kernel_launch(void* const* d_in, const int* in_sizes, int n_in,
                              void* d_out, int out_size, void* d_ws, size_t ws_size,
                              hipStream_t stream)
{
    const float* x   = (const float*)d_in[0];
    const int*   ei  = (const int*)d_in[1];
    const float* W1a = (const float*)d_in[2];
    const float* b1a = (const float*)d_in[3];
    const float* W1b = (const float*)d_in[4];
    const float* b1b = (const float*)d_in[5];
    const float* W2a = (const float*)d_in[6];
    const float* b2a = (const float*)d_in[7];
    const float* W2b = (const float*)d_in[8];
    const float* b2b = (const float*)d_in[9];
    const float* Wl  = (const float*)d_in[10];
    const float* bl  = (const float*)d_in[11];

    const int* src = ei;
    const int* dst = ei + NE;

    float* ws = (float*)d_ws;
    float* A        = ws + A_OFF;
    unsigned* Bu    = (unsigned*)(ws + B_OFF);
    unsigned int* AGG = (unsigned int*)(ws + AGG_OFF);
    int*  gcur  = (int*)(ws + GCUR_OFF);
    int2* p1    = (int2*)(ws + P1_OFF);
    int2* sedge = (int2*)(ws + SEDG_OFF);

    prep_all<<<16, 256, 0, stream>>>(W1a, W1b, W2a, W2b, ws, gcur);
    node_mlp1<<<1564, 256, 0, stream>>>(x, ws + W1D_OFF, ws + W1S_OFF, b1a, A, Bu, (float*)AGG);

    k_bucket <<<782, 256, 0, stream>>>(src, dst, gcur, p1);
    k_sortbkt<<<NB, 256, 0, stream>>>(p1, gcur, sedge);

    edge_layer_mfma<<<NE / 128, 256, 0, stream>>>(A, Bu, sedge,
                                                  (const int*)(ws + WB1F_OFF), b1b, AGG);

    node_mlp2<<<1564, 256, 0, stream>>>((const float*)AGG, ws + W2D_OFF, ws + W2S_OFF, b2a, A, Bu);

    // re-arm AGG for layer 2 via a KERNEL node (memset node mis-ordered in graph)
    k_zero<<<N64 / 1024, 256, 0, stream>>>((float4*)AGG);

    edge_layer_mfma<<<NE / 128, 256, 0, stream>>>(A, Bu, sedge,
                                                  (const int*)(ws + WB2F_OFF), b2b, AGG);

    final_linear<<<391, 256, 0, stream>>>((const float*)AGG, Wl, bl, (float*)d_out);
}

// Round 12
// 322.888 us; speedup vs baseline: 1.3985x; 1.2376x over previous
//
#include <hip/hip_runtime.h>
#include <hip/hip_fp16.h>

#define NN 100000
#define NE 1600000
#define N64 (NN * 64)
#define NB 196                        // buckets = dst>>9 (100000/512)
#define CAP 9216                      // bucket capacity (mean 8192, +11 sigma)
#define MLP_BLKS 1564                 // node-mlp role blocks in fused kernel
#define BKT_BLKS 782                  // bucket role blocks

typedef __attribute__((ext_vector_type(8))) _Float16 f16x8;
typedef __attribute__((ext_vector_type(4))) float fx4;

// ---- workspace layout (dword offsets) ----
#define W1D_OFF 0
#define W1S_OFF 448
#define W2D_OFF 896
#define W2S_OFF 4992
#define WB1F_OFF 9216                 // f16 Wb frags layer1: 2048 dwords
#define WB2F_OFF 11264                // layer2: 2048 dwords
#define GCUR_OFF 17408                // bucket cursors [256]
#define A_OFF   32768                 // A as packed f16: 32 dwords/node
#define B_OFF   (A_OFF + N64 / 2)
#define AGG1_OFF (B_OFF + N64 / 2)
#define AGG2_OFF (AGG1_OFF + N64)
#define P1_OFF  (AGG2_OFF + N64)      // int2[NB*CAP] bucket staging
#define SEDG_OFF (P1_OFF + 2 * NB * CAP)  // int2[NE] sorted edges

union FragH { unsigned u[4]; f16x8 f; };

static __device__ __forceinline__ unsigned pack_h2(float f0, float f1) {
    __half h0 = __float2half_rn(f0), h1 = __float2half_rn(f1);
    unsigned short u0 = *(unsigned short*)&h0, u1 = *(unsigned short*)&h1;
    return (unsigned)u0 | ((unsigned)u1 << 16);
}

// Prep: zero bucket cursors, precombine Wa weights, build f16 Wb MFMA frags.
__global__ __launch_bounds__(256) void prep_all(
    const float* __restrict__ W1a, const float* __restrict__ W1b,
    const float* __restrict__ W2a, const float* __restrict__ W2b,
    float* __restrict__ ws, int* __restrict__ gcur)
{
    int t = blockIdx.x * 256 + threadIdx.x;
    if (t < 256) gcur[t] = 0;
    if (t < 448) {
        float top = W1a[t], bot = W1a[448 + t];
        ws[W1D_OFF + t] = top - bot;
        ws[W1S_OFF + t] = bot;
    }
    if (t < 4096) {
        float top = W2a[t], bot = W2a[4096 + t];
        ws[W2D_OFF + t] = top - bot;
        ws[W2S_OFF + t] = bot;
    }
    // f16 Wb fragments: int4 index r = ks*256 + nt*64 + lane per layer;
    // lane gives k=(lane>>4)*8+j+32ks, n=(lane&15)+16nt, j packed 2/dword.
    if (t < 1024) {
        int layer = t >> 9;
        int r = t & 511;
        int ks = (r >> 8) & 1, nt = (r >> 6) & 3, lane = r & 63;
        const float* Wb = layer ? W2b : W1b;
        int* out = (int*)(ws + (layer ? WB2F_OFF : WB1F_OFF));
        int quad = lane >> 4, c = lane & 15, n = nt * 16 + c;
        unsigned dw[4];
#pragma unroll
        for (int d = 0; d < 4; ++d) {
            int k0 = quad * 8 + d * 2 + 32 * ks;
            dw[d] = pack_h2(Wb[k0 * 64 + n], Wb[(k0 + 1) * 64 + n]);
        }
        ((int4*)out)[r] = make_int4((int)dw[0], (int)dw[1], (int)dw[2], (int)dw[3]);
    }
}

// Fused: blocks [0,MLP_BLKS) run node-MLP1 quarter-split (also zero both AGG
// quarters); blocks [MLP_BLKS, MLP_BLKS+BKT_BLKS) run the bucket multisplit.
// The two roles are data-independent; fusing removes their serialization.
__global__ __launch_bounds__(256) void fused_mlp1_bucket(
    const float* __restrict__ x, const float* __restrict__ Wd,
    const float* __restrict__ Ws, const float* __restrict__ ba,
    unsigned* __restrict__ A16, unsigned* __restrict__ Bu,
    float* __restrict__ agg1, float* __restrict__ agg2,
    const int* __restrict__ src, const int* __restrict__ dst,
    int* __restrict__ gcur, int2* __restrict__ p1)
{
    __shared__ int cnt[NB];
    __shared__ int cur[NB];
    const int t = threadIdx.x;

    if (blockIdx.x < MLP_BLKS) {
        const int q = blockIdx.x & 3;
        const int i = (blockIdx.x >> 2) * 256 + t;
        if (i >= NN) return;
        float xv[7];
#pragma unroll
        for (int k = 0; k < 7; ++k) xv[k] = x[i * 7 + k];

        uint4*  pa = (uint4*)(A16 + (size_t)i * 32 + q * 8);
        uint4*  pb = (uint4*)(Bu + (size_t)i * 32 + q * 8);
        float4* pz1 = (float4*)(agg1 + (size_t)i * 64 + q * 16);
        float4* pz2 = (float4*)(agg2 + (size_t)i * 64 + q * 16);
#pragma unroll
        for (int f = 0; f < 4; ++f) {
            pz1[f] = make_float4(0.f, 0.f, 0.f, 0.f);
            pz2[f] = make_float4(0.f, 0.f, 0.f, 0.f);
        }

        float acc[16];
#pragma unroll
        for (int c = 0; c < 16; ++c) acc[c] = ba[q * 16 + c];
#pragma unroll
        for (int k = 0; k < 7; ++k)
#pragma unroll
            for (int c = 0; c < 16; ++c)
                acc[c] = fmaf(xv[k], Wd[k * 64 + q * 16 + c], acc[c]);
        pa[0] = make_uint4(pack_h2(acc[0], acc[1]),  pack_h2(acc[2], acc[3]),
                           pack_h2(acc[4], acc[5]),  pack_h2(acc[6], acc[7]));
        pa[1] = make_uint4(pack_h2(acc[8], acc[9]),  pack_h2(acc[10], acc[11]),
                           pack_h2(acc[12], acc[13]), pack_h2(acc[14], acc[15]));

#pragma unroll
        for (int c = 0; c < 16; ++c) acc[c] = 0.0f;
#pragma unroll
        for (int k = 0; k < 7; ++k)
#pragma unroll
            for (int c = 0; c < 16; ++c)
                acc[c] = fmaf(xv[k], Ws[k * 64 + q * 16 + c], acc[c]);
        pb[0] = make_uint4(pack_h2(acc[0], acc[1]),  pack_h2(acc[2], acc[3]),
                           pack_h2(acc[4], acc[5]),  pack_h2(acc[6], acc[7]));
        pb[1] = make_uint4(pack_h2(acc[8], acc[9]),  pack_h2(acc[10], acc[11]),
                           pack_h2(acc[12], acc[13]), pack_h2(acc[14], acc[15]));
        return;
    }

    // ---- bucket role ----
    const int bb = blockIdx.x - MLP_BLKS;
    const int e0 = (bb * 256 + t) * 8;
    const bool ok = (e0 < NE);                   // NE % 8 == 0
    if (t < NB) cnt[t] = 0;
    int ss[8], dd[8], bk[8];
    if (ok) {
        int4 d0 = ((const int4*)(dst + e0))[0];
        int4 d1 = ((const int4*)(dst + e0))[1];
        int4 s0 = ((const int4*)(src + e0))[0];
        int4 s1 = ((const int4*)(src + e0))[1];
        dd[0]=d0.x; dd[1]=d0.y; dd[2]=d0.z; dd[3]=d0.w;
        dd[4]=d1.x; dd[5]=d1.y; dd[6]=d1.z; dd[7]=d1.w;
        ss[0]=s0.x; ss[1]=s0.y; ss[2]=s0.z; ss[3]=s0.w;
        ss[4]=s1.x; ss[5]=s1.y; ss[6]=s1.z; ss[7]=s1.w;
    }
    __syncthreads();
    if (ok) {
#pragma unroll
        for (int j = 0; j < 8; ++j) { bk[j] = dd[j] >> 9; atomicAdd(&cnt[bk[j]], 1); }
    }
    __syncthreads();
    if (t < NB) cur[t] = atomicAdd(&gcur[t], cnt[t]);   // reserve block's ranges
    __syncthreads();
    if (ok) {
#pragma unroll
        for (int j = 0; j < 8; ++j) {
            int pos = atomicAdd(&cur[bk[j]], 1);
            p1[(size_t)bk[j] * CAP + pos] = make_int2(ss[j], dd[j]);
        }
    }
}

// Node MLP layer 2, quarter-split: reads full fp32 g row (AGG1), writes f16
// A/Bu quarters. No zeroing (layer-2 aggregation goes to AGG2).
__global__ __launch_bounds__(256) void node_mlp2(
    const float* __restrict__ g, const float* __restrict__ Wd,
    const float* __restrict__ Ws, const float* __restrict__ ba2,
    unsigned* __restrict__ A16, unsigned* __restrict__ Bu)
{
    const int q = blockIdx.x & 3;
    const int i = (blockIdx.x >> 2) * 256 + threadIdx.x;
    if (i >= NN) return;
    float gv[64];
    const float4* pg = (const float4*)(g + (size_t)i * 64);
#pragma unroll
    for (int r = 0; r < 16; ++r) {
        float4 v = pg[r];
        gv[r*4+0] = v.x; gv[r*4+1] = v.y; gv[r*4+2] = v.z; gv[r*4+3] = v.w;
    }
    uint4* pa = (uint4*)(A16 + (size_t)i * 32 + q * 8);
    uint4* pb = (uint4*)(Bu + (size_t)i * 32 + q * 8);

    float acc[16];
#pragma unroll
    for (int c = 0; c < 16; ++c) acc[c] = ba2[q * 16 + c];
#pragma unroll
    for (int j = 0; j < 64; ++j)
#pragma unroll
        for (int c = 0; c < 16; ++c)
            acc[c] = fmaf(gv[j], Wd[j * 64 + q * 16 + c], acc[c]);
    pa[0] = make_uint4(pack_h2(acc[0], acc[1]),  pack_h2(acc[2], acc[3]),
                       pack_h2(acc[4], acc[5]),  pack_h2(acc[6], acc[7]));
    pa[1] = make_uint4(pack_h2(acc[8], acc[9]),  pack_h2(acc[10], acc[11]),
                       pack_h2(acc[12], acc[13]), pack_h2(acc[14], acc[15]));

#pragma unroll
    for (int c = 0; c < 16; ++c) acc[c] = 0.0f;
#pragma unroll
    for (int j = 0; j < 64; ++j)
#pragma unroll
        for (int c = 0; c < 16; ++c)
            acc[c] = fmaf(gv[j], Ws[j * 64 + q * 16 + c], acc[c]);
    pb[0] = make_uint4(pack_h2(acc[0], acc[1]),  pack_h2(acc[2], acc[3]),
                       pack_h2(acc[4], acc[5]),  pack_h2(acc[6], acc[7]));
    pb[1] = make_uint4(pack_h2(acc[8], acc[9]),  pack_h2(acc[10], acc[11]),
                       pack_h2(acc[12], acc[13]), pack_h2(acc[14], acc[15]));
}

// Sort pass 2: one block per bucket, counting sort by low 9 bits in LDS.
__global__ __launch_bounds__(256) void k_sortbkt(
    const int2* __restrict__ p1, const int* __restrict__ gcnt,
    int2* __restrict__ sedge)
{
    __shared__ int sz[256];
    __shared__ int cnt[512];
    __shared__ int cur[512];
    __shared__ int pairb[256];
    const int b = blockIdx.x, t = threadIdx.x;
    sz[t] = (t < NB) ? gcnt[t] : 0;
    cnt[t] = 0; cnt[t + 256] = 0;
    __syncthreads();
#pragma unroll
    for (int off = 1; off < 256; off <<= 1) {       // inclusive scan of bucket sizes
        int u = (t >= off) ? sz[t - off] : 0;
        __syncthreads();
        sz[t] += u;
        __syncthreads();
    }
    const int myBase = (b == 0) ? 0 : sz[b - 1];
    const int mySize = gcnt[b];
    const int2* bp = p1 + (size_t)b * CAP;
    for (int i = t; i < mySize; i += 256) atomicAdd(&cnt[bp[i].y & 511], 1);
    __syncthreads();
    pairb[t] = cnt[2 * t] + cnt[2 * t + 1];
    __syncthreads();
#pragma unroll
    for (int off = 1; off < 256; off <<= 1) {       // scan pair-sums
        int u = (t >= off) ? pairb[t - off] : 0;
        __syncthreads();
        pairb[t] += u;
        __syncthreads();
    }
    int ex = (t == 0) ? 0 : pairb[t - 1];
    cur[2 * t] = ex;
    cur[2 * t + 1] = ex + cnt[2 * t];
    __syncthreads();
    for (int i = t; i < mySize; i += 256) {
        int2 e = bp[i];
        int pos = atomicAdd(&cur[e.y & 511], 1);
        sedge[(size_t)myBase + pos] = e;
    }
}

// MFMA edge layer: wave = 32 edges. A and B both packed f16 -> t = relu(a+b)
// via native _Float16 vector ops (v_pk_add_f16 / v_pk_max_f16) feeds
// mfma_f32_16x16x32_f16 DIRECTLY (single pass, no bf16 split, no converts).
// W pre-converted to f16-RN frags (rel err 2^-12).
__global__ __launch_bounds__(256, 3) void edge_layer_mfma(
    const unsigned* __restrict__ A16, const unsigned* __restrict__ Bu,
    const int2* __restrict__ se,
    const int* __restrict__ wbf, const float* __restrict__ bb,
    unsigned int* __restrict__ agg)
{
    __shared__ int lds[4][1024];           // per wave: 16-edge epilogue chunk
    const int tid = threadIdx.x;
    const int wv = tid >> 6, lane = tid & 63;
    int* chunk = lds[wv];
    const int quad = lane >> 4, c15 = lane & 15;
    const int base = (blockIdx.x * 4 + wv) * 32;

    int2 ed  = se[base + (lane & 31)];     // this wave's 32 edges (dup in hi half)
    int2 eb0 = se[base + c15];             // fragment-row edge, mt=0 (quad-uniform)
    int2 eb1 = se[base + 16 + c15];        // mt=1

    const unsigned* pa0 = A16 + (size_t)eb0.y * 32 + quad * 4;
    const unsigned* pb0 = Bu  + (size_t)eb0.x * 32 + quad * 4;
    const unsigned* pa1 = A16 + (size_t)eb1.y * 32 + quad * 4;
    const unsigned* pb1 = Bu  + (size_t)eb1.x * 32 + quad * 4;

    // front-load ALL gathers: 1 uint4 per (mt,ks) for A and B
    uint4 ga[2][2], gb[2][2];
#pragma unroll
    for (int ks = 0; ks < 2; ++ks) {
        ga[0][ks] = ((const uint4*)(pa0 + ks * 16))[0];
        gb[0][ks] = ((const uint4*)(pb0 + ks * 16))[0];
        ga[1][ks] = ((const uint4*)(pa1 + ks * 16))[0];
        gb[1][ks] = ((const uint4*)(pb1 + ks * 16))[0];
    }

    // t = relu(a+b) in packed f16 (native vector ops) -> MFMA A-operand frags
    FragH tf[2][2];
#pragma unroll
    for (int mt = 0; mt < 2; ++mt)
#pragma unroll
        for (int ks = 0; ks < 2; ++ks) {
            FragH ua, ub;
            ua.u[0] = ga[mt][ks].x; ua.u[1] = ga[mt][ks].y;
            ua.u[2] = ga[mt][ks].z; ua.u[3] = ga[mt][ks].w;
            ub.u[0] = gb[mt][ks].x; ub.u[1] = gb[mt][ks].y;
            ub.u[2] = gb[mt][ks].z; ub.u[3] = gb[mt][ks].w;
            f16x8 s = ua.f + ub.f;
            tf[mt][ks].f = __builtin_elementwise_max(s, (f16x8)(_Float16)0.0f);
        }

    fx4 acc[2][4];
#pragma unroll
    for (int mt = 0; mt < 2; ++mt)
#pragma unroll
        for (int nt = 0; nt < 4; ++nt)
            acc[mt][nt] = (fx4){0.f, 0.f, 0.f, 0.f};

#pragma unroll
    for (int ks = 0; ks < 2; ++ks) {
        FragH wf[4];
#pragma unroll
        for (int nt = 0; nt < 4; ++nt) {
            int4 v = ((const int4*)wbf)[(ks * 4 + nt) * 64 + lane];
            wf[nt].u[0] = (unsigned)v.x; wf[nt].u[1] = (unsigned)v.y;
            wf[nt].u[2] = (unsigned)v.z; wf[nt].u[3] = (unsigned)v.w;
        }
#pragma unroll
        for (int mt = 0; mt < 2; ++mt)
#pragma unroll
            for (int nt = 0; nt < 4; ++nt)
                acc[mt][nt] = __builtin_amdgcn_mfma_f32_16x16x32_f16(
                    tf[mt][ks].f, wf[nt].f, acc[mt][nt], 0, 0, 0);
    }

    // epilogue: bias+relu, 16-edge LDS chunks (2-way-max bank swizzle), segmented max
    float bbv[4];
#pragma unroll
    for (int nt = 0; nt < 4; ++nt) bbv[nt] = bb[nt * 16 + c15];

    int dprev = __builtin_amdgcn_readlane(ed.y, 0);
    float run = 0.f;
#pragma unroll
    for (int mt = 0; mt < 2; ++mt) {
#pragma unroll
        for (int nt = 0; nt < 4; ++nt)
#pragma unroll
            for (int r = 0; r < 4; ++r) {
                int ee = mt * 16 + quad * 4 + r;
                int ch = nt * 16 + c15;
                float h = fmaxf(acc[mt][nt][r] + bbv[nt], 0.f);
                chunk[(ee & 15) * 64 + ((ch + 4 * ee) & 63)] = __float_as_int(h);
            }
#pragma unroll
        for (int i = 0; i < 16; ++i) {
            int ee = mt * 16 + i;
            float v = __int_as_float(chunk[i * 64 + ((lane + 4 * ee) & 63)]);
            int dd = __builtin_amdgcn_readlane(ed.y, ee);
            if (dd != dprev) {
                atomicMax(&agg[(size_t)dprev * 64 + lane], __float_as_uint(run));
                run = 0.f; dprev = dd;
            }
            run = fmaxf(run, v);
        }
    }
    atomicMax(&agg[(size_t)dprev * 64 + lane], __float_as_uint(run));
}

// out[i] = h2[i,:] @ Wl + bl
__global__ __launch_bounds__(256) void final_linear(
    const float* __restrict__ h2, const float* __restrict__ Wl,
    const float* __restrict__ bl, float* __restrict__ out)
{
    int i = blockIdx.x * 256 + threadIdx.x;
    if (i >= NN) return;
    const float4* row = (const float4*)(h2 + (size_t)i * 64);
    float acc = bl[0];
#pragma unroll
    for (int q = 0; q < 16; ++q) {
        float4 v = row[q];
        acc = fmaf(v.x, Wl[q * 4 + 0], acc);
        acc = fmaf(v.y, Wl[q * 4 + 1], acc);
        acc = fmaf(v.z, Wl[q * 4 + 2], acc);
        acc = fmaf(v.w, Wl[q * 4 + 3], acc);
    }
    out[i] = acc;
}

extern "C" void kernel_launch(void* const* d_in, const int* in_sizes, int n_in,
                              void* d_out, int out_size, void* d_ws, size_t ws_size,
                              hipStream_t stream)
{
    const float* x   = (const float*)d_in[0];
    const int*   ei  = (const int*)d_in[1];
    const float* W1a = (const float*)d_in[2];
    const float* b1a = (const float*)d_in[3];
    const float* W1b = (const float*)d_in[4];
    const float* b1b = (const float*)d_in[5];
    const float* W2a = (const float*)d_in[6];
    const float* b2a = (const float*)d_in[7];
    const float* W2b = (const float*)d_in[8];
    const float* b2b = (const float*)d_in[9];
    const float* Wl  = (const float*)d_in[10];
    const float* bl  = (const float*)d_in[11];

    const int* src = ei;
    const int* dst = ei + NE;

    float* ws = (float*)d_ws;
    unsigned* A16 = (unsigned*)(ws + A_OFF);
    unsigned* Bu  = (unsigned*)(ws + B_OFF);
    unsigned int* AGG1 = (unsigned int*)(ws + AGG1_OFF);
    unsigned int* AGG2 = (unsigned int*)(ws + AGG2_OFF);
    int*  gcur  = (int*)(ws + GCUR_OFF);
    int2* p1    = (int2*)(ws + P1_OFF);
    int2* sedge = (int2*)(ws + SEDG_OFF);

    prep_all<<<16, 256, 0, stream>>>(W1a, W1b, W2a, W2b, ws, gcur);

    fused_mlp1_bucket<<<MLP_BLKS + BKT_BLKS, 256, 0, stream>>>(
        x, ws + W1D_OFF, ws + W1S_OFF, b1a, A16, Bu,
        (float*)AGG1, (float*)AGG2, src, dst, gcur, p1);

    k_sortbkt<<<NB, 256, 0, stream>>>(p1, gcur, sedge);

    edge_layer_mfma<<<NE / 128, 256, 0, stream>>>(A16, Bu, sedge,
                                                  (const int*)(ws + WB1F_OFF), b1b, AGG1);

    node_mlp2<<<MLP_BLKS, 256, 0, stream>>>((const float*)AGG1,
                                            ws + W2D_OFF, ws + W2S_OFF, b2a, A16, Bu);

    edge_layer_mfma<<<NE / 128, 256, 0, stream>>>(A16, Bu, sedge,
                                                  (const int*)(ws + WB2F_OFF), b2b, AGG2);

    final_linear<<<391, 256, 0, stream>>>((const float*)AGG2, Wl, bl, (float*)d_out);
}

// Round 13
// 281.041 us; speedup vs baseline: 1.6067x; 1.1489x over previous
//
#include <hip/hip_runtime.h>
#include <hip/hip_fp16.h>

#define NN 100000
#define NE 1600000
#define N64 (NN * 64)
#define NB 196                        // buckets = dst>>9 (100000/512)
#define CAP 9216                      // bucket capacity (mean 8192, +11 sigma)
#define MLP_BLKS 1564                 // node-mlp role blocks in fused kernel
#define BKT_BLKS 782                  // bucket role blocks

typedef __attribute__((ext_vector_type(8))) _Float16 f16x8;
typedef __attribute__((ext_vector_type(4))) float fx4;

// ---- workspace layout (dword offsets) ----
#define W1D_OFF 0
#define W1S_OFF 448
#define WB1F_OFF 9216                 // f16 Wb frags layer1: 2048 dwords
#define WB2F_OFF 11264                // layer2: 2048 dwords
#define W2C_OFF 13312                 // combined f16 W2a frags (Wd||Ws): 4096 dwords
#define GCUR_OFF 17408                // bucket cursors [256]
#define A_OFF   32768                 // A as packed f16: 32 dwords/node
#define B_OFF   (A_OFF + N64 / 2)
#define AGG1_OFF (B_OFF + N64 / 2)
#define AGG2_OFF (AGG1_OFF + N64)
#define P1_OFF  (AGG2_OFF + N64)      // int2[NB*CAP] bucket staging
#define SEDG_OFF (P1_OFF + 2 * NB * CAP)  // int2[NE] sorted edges

union FragH { unsigned u[4]; f16x8 f; };

static __device__ __forceinline__ unsigned pack_h2(float f0, float f1) {
    __half h0 = __float2half_rn(f0), h1 = __float2half_rn(f1);
    unsigned short u0 = *(unsigned short*)&h0, u1 = *(unsigned short*)&h1;
    return (unsigned)u0 | ((unsigned)u1 << 16);
}

// Prep: zero bucket cursors, precombine W1a weights, build f16 Wb frags and
// the combined layer-2 node-MLP weight frags (Wd = top-bottom || Ws = bottom).
__global__ __launch_bounds__(256) void prep_all(
    const float* __restrict__ W1a, const float* __restrict__ W1b,
    const float* __restrict__ W2a, const float* __restrict__ W2b,
    float* __restrict__ ws, int* __restrict__ gcur)
{
    int t = blockIdx.x * 256 + threadIdx.x;
    if (t < 256) gcur[t] = 0;
    if (t < 448) {
        float top = W1a[t], bot = W1a[448 + t];
        ws[W1D_OFF + t] = top - bot;
        ws[W1S_OFF + t] = bot;
    }
    // f16 Wb fragments (edge layers): int4 index r = ks*256 + nt*64 + lane;
    // lane gives k=(lane>>4)*8+j+32ks, n=(lane&15)+16nt, j packed 2/dword.
    if (t < 1024) {
        int layer = t >> 9;
        int r = t & 511;
        int ks = (r >> 8) & 1, nt = (r >> 6) & 3, lane = r & 63;
        const float* Wb = layer ? W2b : W1b;
        int* out = (int*)(ws + (layer ? WB2F_OFF : WB1F_OFF));
        int quad = lane >> 4, c = lane & 15, n = nt * 16 + c;
        unsigned dw[4];
#pragma unroll
        for (int d = 0; d < 4; ++d) {
            int k0 = quad * 8 + d * 2 + 32 * ks;
            dw[d] = pack_h2(Wb[k0 * 64 + n], Wb[(k0 + 1) * 64 + n]);
        }
        ((int4*)out)[r] = make_int4((int)dw[0], (int)dw[1], (int)dw[2], (int)dw[3]);
    }
    // combined node-MLP2 weight frags: N=128 (cols 0..63 -> Wd, 64..127 -> Ws)
    if (t >= 1024 && t < 2048) {
        int r = t - 1024;                       // ks*512 + nt*64 + lane
        int ks = (r >> 9) & 1, nt8 = (r >> 6) & 7, lane = r & 63;
        int quad = lane >> 4, c = lane & 15;
        int ncol = nt8 * 16 + c;                // 0..127
        int* out = (int*)(ws + W2C_OFF);
        unsigned dw[4];
#pragma unroll
        for (int d = 0; d < 4; ++d) {
            unsigned v[2];
#pragma unroll
            for (int e = 0; e < 2; ++e) {
                int k = quad * 8 + d * 2 + e + 32 * ks;
                float w = (ncol < 64)
                    ? (W2a[k * 64 + ncol] - W2a[(64 + k) * 64 + ncol])
                    : W2a[(64 + k) * 64 + (ncol - 64)];
                __half h = __float2half_rn(w);
                v[e] = *(unsigned short*)&h;
            }
            dw[d] = (v[1] << 16) | v[0];
        }
        ((int4*)out)[r] = make_int4((int)dw[0], (int)dw[1], (int)dw[2], (int)dw[3]);
    }
}

// Fused: blocks [0,MLP_BLKS) run node-MLP1 quarter-split (also zero both AGG
// quarters); blocks [MLP_BLKS, MLP_BLKS+BKT_BLKS) run the bucket multisplit.
__global__ __launch_bounds__(256) void fused_mlp1_bucket(
    const float* __restrict__ x, const float* __restrict__ Wd,
    const float* __restrict__ Ws, const float* __restrict__ ba,
    unsigned* __restrict__ A16, unsigned* __restrict__ Bu,
    float* __restrict__ agg1, float* __restrict__ agg2,
    const int* __restrict__ src, const int* __restrict__ dst,
    int* __restrict__ gcur, int2* __restrict__ p1)
{
    __shared__ int cnt[NB];
    __shared__ int cur[NB];
    const int t = threadIdx.x;

    if (blockIdx.x < MLP_BLKS) {
        const int q = blockIdx.x & 3;
        const int i = (blockIdx.x >> 2) * 256 + t;
        if (i >= NN) return;
        float xv[7];
#pragma unroll
        for (int k = 0; k < 7; ++k) xv[k] = x[i * 7 + k];

        uint4*  pa = (uint4*)(A16 + (size_t)i * 32 + q * 8);
        uint4*  pb = (uint4*)(Bu + (size_t)i * 32 + q * 8);
        float4* pz1 = (float4*)(agg1 + (size_t)i * 64 + q * 16);
        float4* pz2 = (float4*)(agg2 + (size_t)i * 64 + q * 16);
#pragma unroll
        for (int f = 0; f < 4; ++f) {
            pz1[f] = make_float4(0.f, 0.f, 0.f, 0.f);
            pz2[f] = make_float4(0.f, 0.f, 0.f, 0.f);
        }

        float acc[16];
#pragma unroll
        for (int c = 0; c < 16; ++c) acc[c] = ba[q * 16 + c];
#pragma unroll
        for (int k = 0; k < 7; ++k)
#pragma unroll
            for (int c = 0; c < 16; ++c)
                acc[c] = fmaf(xv[k], Wd[k * 64 + q * 16 + c], acc[c]);
        pa[0] = make_uint4(pack_h2(acc[0], acc[1]),  pack_h2(acc[2], acc[3]),
                           pack_h2(acc[4], acc[5]),  pack_h2(acc[6], acc[7]));
        pa[1] = make_uint4(pack_h2(acc[8], acc[9]),  pack_h2(acc[10], acc[11]),
                           pack_h2(acc[12], acc[13]), pack_h2(acc[14], acc[15]));

#pragma unroll
        for (int c = 0; c < 16; ++c) acc[c] = 0.0f;
#pragma unroll
        for (int k = 0; k < 7; ++k)
#pragma unroll
            for (int c = 0; c < 16; ++c)
                acc[c] = fmaf(xv[k], Ws[k * 64 + q * 16 + c], acc[c]);
        pb[0] = make_uint4(pack_h2(acc[0], acc[1]),  pack_h2(acc[2], acc[3]),
                           pack_h2(acc[4], acc[5]),  pack_h2(acc[6], acc[7]));
        pb[1] = make_uint4(pack_h2(acc[8], acc[9]),  pack_h2(acc[10], acc[11]),
                           pack_h2(acc[12], acc[13]), pack_h2(acc[14], acc[15]));
        return;
    }

    // ---- bucket role ----
    const int bb = blockIdx.x - MLP_BLKS;
    const int e0 = (bb * 256 + t) * 8;
    const bool ok = (e0 < NE);                   // NE % 8 == 0
    if (t < NB) cnt[t] = 0;
    int ss[8], dd[8], bk[8];
    if (ok) {
        int4 d0 = ((const int4*)(dst + e0))[0];
        int4 d1 = ((const int4*)(dst + e0))[1];
        int4 s0 = ((const int4*)(src + e0))[0];
        int4 s1 = ((const int4*)(src + e0))[1];
        dd[0]=d0.x; dd[1]=d0.y; dd[2]=d0.z; dd[3]=d0.w;
        dd[4]=d1.x; dd[5]=d1.y; dd[6]=d1.z; dd[7]=d1.w;
        ss[0]=s0.x; ss[1]=s0.y; ss[2]=s0.z; ss[3]=s0.w;
        ss[4]=s1.x; ss[5]=s1.y; ss[6]=s1.z; ss[7]=s1.w;
    }
    __syncthreads();
    if (ok) {
#pragma unroll
        for (int j = 0; j < 8; ++j) { bk[j] = dd[j] >> 9; atomicAdd(&cnt[bk[j]], 1); }
    }
    __syncthreads();
    if (t < NB) cur[t] = atomicAdd(&gcur[t], cnt[t]);   // reserve block's ranges
    __syncthreads();
    if (ok) {
#pragma unroll
        for (int j = 0; j < 8; ++j) {
            int pos = atomicAdd(&cur[bk[j]], 1);
            p1[(size_t)bk[j] * CAP + pos] = make_int2(ss[j], dd[j]);
        }
    }
}

// Node MLP layer 2 as MFMA GEMM: [NN x 64] @ [64 x 128] (Wd || Ws).
// Wave = 32 nodes x 128 channels; g read ONCE (fp32 -> f16-RN in-register);
// epilogue adds ba2 on the A half and stores f16 scalars.
__global__ __launch_bounds__(256, 3) void node_mlp2_mfma(
    const float* __restrict__ g, const int* __restrict__ wcf,
    const float* __restrict__ ba2,
    unsigned* __restrict__ A16, unsigned* __restrict__ Bu)
{
    const int tid = threadIdx.x;
    const int wv = tid >> 6, lane = tid & 63;
    const int quad = lane >> 4, c15 = lane & 15;
    const int wid = blockIdx.x * 4 + wv;
    const int nbase = wid * 32;
    if (nbase >= NN) return;            // 100000/32 = 3125 full waves exactly

    // A-frags: rows nbase+16mt+c15, cols 32ks + 8*quad .. +8 (fp32 -> f16 RN)
    FragH tf[2][2];
#pragma unroll
    for (int mt = 0; mt < 2; ++mt) {
        const float* pr = g + (size_t)(nbase + mt * 16 + c15) * 64 + quad * 8;
#pragma unroll
        for (int ks = 0; ks < 2; ++ks) {
            float4 a0 = ((const float4*)(pr + ks * 32))[0];
            float4 a1 = ((const float4*)(pr + ks * 32))[1];
            tf[mt][ks].u[0] = pack_h2(a0.x, a0.y);
            tf[mt][ks].u[1] = pack_h2(a0.z, a0.w);
            tf[mt][ks].u[2] = pack_h2(a1.x, a1.y);
            tf[mt][ks].u[3] = pack_h2(a1.z, a1.w);
        }
    }

    fx4 acc[2][8];
#pragma unroll
    for (int mt = 0; mt < 2; ++mt)
#pragma unroll
        for (int nt = 0; nt < 8; ++nt)
            acc[mt][nt] = (fx4){0.f, 0.f, 0.f, 0.f};

#pragma unroll
    for (int ks = 0; ks < 2; ++ks) {
        FragH wf[8];
#pragma unroll
        for (int nt = 0; nt < 8; ++nt) {
            int4 v = ((const int4*)wcf)[(ks * 8 + nt) * 64 + lane];
            wf[nt].u[0] = (unsigned)v.x; wf[nt].u[1] = (unsigned)v.y;
            wf[nt].u[2] = (unsigned)v.z; wf[nt].u[3] = (unsigned)v.w;
        }
#pragma unroll
        for (int mt = 0; mt < 2; ++mt)
#pragma unroll
            for (int nt = 0; nt < 8; ++nt)
                acc[mt][nt] = __builtin_amdgcn_mfma_f32_16x16x32_f16(
                    tf[mt][ks].f, wf[nt].f, acc[mt][nt], 0, 0, 0);
    }

    // epilogue: D row = node 16mt+4*quad+r, col = ch 16*(nt&3)+c15.
    __half* Ah = (__half*)A16;
    __half* Bh = (__half*)Bu;
#pragma unroll
    for (int nt = 0; nt < 8; ++nt) {
        float bb = (nt < 4) ? ba2[nt * 16 + c15] : 0.f;
        __half* out = (nt < 4) ? Ah : Bh;
        int ch = (nt & 3) * 16 + c15;
#pragma unroll
        for (int mt = 0; mt < 2; ++mt)
#pragma unroll
            for (int r = 0; r < 4; ++r) {
                int node = nbase + mt * 16 + quad * 4 + r;
                out[(size_t)node * 64 + ch] = __float2half_rn(acc[mt][nt][r] + bb);
            }
    }
}

// Sort pass 2: one block per bucket, counting sort by low 9 bits in LDS.
__global__ __launch_bounds__(256) void k_sortbkt(
    const int2* __restrict__ p1, const int* __restrict__ gcnt,
    int2* __restrict__ sedge)
{
    __shared__ int sz[256];
    __shared__ int cnt[512];
    __shared__ int cur[512];
    __shared__ int pairb[256];
    const int b = blockIdx.x, t = threadIdx.x;
    sz[t] = (t < NB) ? gcnt[t] : 0;
    cnt[t] = 0; cnt[t + 256] = 0;
    __syncthreads();
#pragma unroll
    for (int off = 1; off < 256; off <<= 1) {       // inclusive scan of bucket sizes
        int u = (t >= off) ? sz[t - off] : 0;
        __syncthreads();
        sz[t] += u;
        __syncthreads();
    }
    const int myBase = (b == 0) ? 0 : sz[b - 1];
    const int mySize = gcnt[b];
    const int2* bp = p1 + (size_t)b * CAP;
    for (int i = t; i < mySize; i += 256) atomicAdd(&cnt[bp[i].y & 511], 1);
    __syncthreads();
    pairb[t] = cnt[2 * t] + cnt[2 * t + 1];
    __syncthreads();
#pragma unroll
    for (int off = 1; off < 256; off <<= 1) {       // scan pair-sums
        int u = (t >= off) ? pairb[t - off] : 0;
        __syncthreads();
        pairb[t] += u;
        __syncthreads();
    }
    int ex = (t == 0) ? 0 : pairb[t - 1];
    cur[2 * t] = ex;
    cur[2 * t + 1] = ex + cnt[2 * t];
    __syncthreads();
    for (int i = t; i < mySize; i += 256) {
        int2 e = bp[i];
        int pos = atomicAdd(&cur[e.y & 511], 1);
        sedge[(size_t)myBase + pos] = e;
    }
}

// MFMA edge layer: wave = 32 edges. A and B both packed f16 -> t = relu(a+b)
// via native _Float16 vector ops feeds mfma_f32_16x16x32_f16 directly.
__global__ __launch_bounds__(256, 3) void edge_layer_mfma(
    const unsigned* __restrict__ A16, const unsigned* __restrict__ Bu,
    const int2* __restrict__ se,
    const int* __restrict__ wbf, const float* __restrict__ bb,
    unsigned int* __restrict__ agg)
{
    __shared__ int lds[4][1024];           // per wave: 16-edge epilogue chunk
    const int tid = threadIdx.x;
    const int wv = tid >> 6, lane = tid & 63;
    int* chunk = lds[wv];
    const int quad = lane >> 4, c15 = lane & 15;
    const int base = (blockIdx.x * 4 + wv) * 32;

    int2 ed  = se[base + (lane & 31)];     // this wave's 32 edges (dup in hi half)
    int2 eb0 = se[base + c15];             // fragment-row edge, mt=0 (quad-uniform)
    int2 eb1 = se[base + 16 + c15];        // mt=1

    const unsigned* pa0 = A16 + (size_t)eb0.y * 32 + quad * 4;
    const unsigned* pb0 = Bu  + (size_t)eb0.x * 32 + quad * 4;
    const unsigned* pa1 = A16 + (size_t)eb1.y * 32 + quad * 4;
    const unsigned* pb1 = Bu  + (size_t)eb1.x * 32 + quad * 4;

    // front-load ALL gathers: 1 uint4 per (mt,ks) for A and B
    uint4 ga[2][2], gb[2][2];
#pragma unroll
    for (int ks = 0; ks < 2; ++ks) {
        ga[0][ks] = ((const uint4*)(pa0 + ks * 16))[0];
        gb[0][ks] = ((const uint4*)(pb0 + ks * 16))[0];
        ga[1][ks] = ((const uint4*)(pa1 + ks * 16))[0];
        gb[1][ks] = ((const uint4*)(pb1 + ks * 16))[0];
    }

    // t = relu(a+b) in packed f16 (native vector ops) -> MFMA A-operand frags
    FragH tf[2][2];
#pragma unroll
    for (int mt = 0; mt < 2; ++mt)
#pragma unroll
        for (int ks = 0; ks < 2; ++ks) {
            FragH ua, ub;
            ua.u[0] = ga[mt][ks].x; ua.u[1] = ga[mt][ks].y;
            ua.u[2] = ga[mt][ks].z; ua.u[3] = ga[mt][ks].w;
            ub.u[0] = gb[mt][ks].x; ub.u[1] = gb[mt][ks].y;
            ub.u[2] = gb[mt][ks].z; ub.u[3] = gb[mt][ks].w;
            f16x8 s = ua.f + ub.f;
            tf[mt][ks].f = __builtin_elementwise_max(s, (f16x8)(_Float16)0.0f);
        }

    fx4 acc[2][4];
#pragma unroll
    for (int mt = 0; mt < 2; ++mt)
#pragma unroll
        for (int nt = 0; nt < 4; ++nt)
            acc[mt][nt] = (fx4){0.f, 0.f, 0.f, 0.f};

#pragma unroll
    for (int ks = 0; ks < 2; ++ks) {
        FragH wf[4];
#pragma unroll
        for (int nt = 0; nt < 4; ++nt) {
            int4 v = ((const int4*)wbf)[(ks * 4 + nt) * 64 + lane];
            wf[nt].u[0] = (unsigned)v.x; wf[nt].u[1] = (unsigned)v.y;
            wf[nt].u[2] = (unsigned)v.z; wf[nt].u[3] = (unsigned)v.w;
        }
#pragma unroll
        for (int mt = 0; mt < 2; ++mt)
#pragma unroll
            for (int nt = 0; nt < 4; ++nt)
                acc[mt][nt] = __builtin_amdgcn_mfma_f32_16x16x32_f16(
                    tf[mt][ks].f, wf[nt].f, acc[mt][nt], 0, 0, 0);
    }

    // epilogue: bias+relu, 16-edge LDS chunks (2-way-max bank swizzle), segmented max
    float bbv[4];
#pragma unroll
    for (int nt = 0; nt < 4; ++nt) bbv[nt] = bb[nt * 16 + c15];

    int dprev = __builtin_amdgcn_readlane(ed.y, 0);
    float run = 0.f;
#pragma unroll
    for (int mt = 0; mt < 2; ++mt) {
#pragma unroll
        for (int nt = 0; nt < 4; ++nt)
#pragma unroll
            for (int r = 0; r < 4; ++r) {
                int ee = mt * 16 + quad * 4 + r;
                int ch = nt * 16 + c15;
                float h = fmaxf(acc[mt][nt][r] + bbv[nt], 0.f);
                chunk[(ee & 15) * 64 + ((ch + 4 * ee) & 63)] = __float_as_int(h);
            }
#pragma unroll
        for (int i = 0; i < 16; ++i) {
            int ee = mt * 16 + i;
            float v = __int_as_float(chunk[i * 64 + ((lane + 4 * ee) & 63)]);
            int dd = __builtin_amdgcn_readlane(ed.y, ee);
            if (dd != dprev) {
                atomicMax(&agg[(size_t)dprev * 64 + lane], __float_as_uint(run));
                run = 0.f; dprev = dd;
            }
            run = fmaxf(run, v);
        }
    }
    atomicMax(&agg[(size_t)dprev * 64 + lane], __float_as_uint(run));
}

// out[i] = h2[i,:] @ Wl + bl
__global__ __launch_bounds__(256) void final_linear(
    const float* __restrict__ h2, const float* __restrict__ Wl,
    const float* __restrict__ bl, float* __restrict__ out)
{
    int i = blockIdx.x * 256 + threadIdx.x;
    if (i >= NN) return;
    const float4* row = (const float4*)(h2 + (size_t)i * 64);
    float acc = bl[0];
#pragma unroll
    for (int q = 0; q < 16; ++q) {
        float4 v = row[q];
        acc = fmaf(v.x, Wl[q * 4 + 0], acc);
        acc = fmaf(v.y, Wl[q * 4 + 1], acc);
        acc = fmaf(v.z, Wl[q * 4 + 2], acc);
        acc = fmaf(v.w, Wl[q * 4 + 3], acc);
    }
    out[i] = acc;
}

extern "C" void kernel_launch(void* const* d_in, const int* in_sizes, int n_in,
                              void* d_out, int out_size, void* d_ws, size_t ws_size,
                              hipStream_t stream)
{
    const float* x   = (const float*)d_in[0];
    const int*   ei  = (const int*)d_in[1];
    const float* W1a = (const float*)d_in[2];
    const float* b1a = (const float*)d_in[3];
    const float* W1b = (const float*)d_in[4];
    const float* b1b = (const float*)d_in[5];
    const float* W2a = (const float*)d_in[6];
    const float* b2a = (const float*)d_in[7];
    const float* W2b = (const float*)d_in[8];
    const float* b2b = (const float*)d_in[9];
    const float* Wl  = (const float*)d_in[10];
    const float* bl  = (const float*)d_in[11];

    const int* src = ei;
    const int* dst = ei + NE;

    float* ws = (float*)d_ws;
    unsigned* A16 = (unsigned*)(ws + A_OFF);
    unsigned* Bu  = (unsigned*)(ws + B_OFF);
    unsigned int* AGG1 = (unsigned int*)(ws + AGG1_OFF);
    unsigned int* AGG2 = (unsigned int*)(ws + AGG2_OFF);
    int*  gcur  = (int*)(ws + GCUR_OFF);
    int2* p1    = (int2*)(ws + P1_OFF);
    int2* sedge = (int2*)(ws + SEDG_OFF);

    prep_all<<<16, 256, 0, stream>>>(W1a, W1b, W2a, W2b, ws, gcur);

    fused_mlp1_bucket<<<MLP_BLKS + BKT_BLKS, 256, 0, stream>>>(
        x, ws + W1D_OFF, ws + W1S_OFF, b1a, A16, Bu,
        (float*)AGG1, (float*)AGG2, src, dst, gcur, p1);

    k_sortbkt<<<NB, 256, 0, stream>>>(p1, gcur, sedge);

    edge_layer_mfma<<<NE / 128, 256, 0, stream>>>(A16, Bu, sedge,
                                                  (const int*)(ws + WB1F_OFF), b1b, AGG1);

    node_mlp2_mfma<<<782, 256, 0, stream>>>((const float*)AGG1,
                                            (const int*)(ws + W2C_OFF), b2a, A16, Bu);

    edge_layer_mfma<<<NE / 128, 256, 0, stream>>>(A16, Bu, sedge,
                                                  (const int*)(ws + WB2F_OFF), b2b, AGG2);

    final_linear<<<391, 256, 0, stream>>>((const float*)AGG2, Wl, bl, (float*)d_out);
}

// Round 14
// 277.008 us; speedup vs baseline: 1.6301x; 1.0146x over previous
//
#include <hip/hip_runtime.h>
#include <hip/hip_fp16.h>

#define NN 100000
#define NE 1600000
#define N64 (NN * 64)
#define NB 782                        // buckets = dst>>7 (ceil(100000/128))
#define CAP2 2432                     // bucket capacity (mean ~2048, > +8 sigma)
#define MLP1_BLKS 391                 // mlp1 role: block covers 256 nodes x 4 quarters
#define BKT_BLKS 196                  // 196 * 1024 * 8 >= NE

typedef __attribute__((ext_vector_type(8))) _Float16 f16x8;
typedef __attribute__((ext_vector_type(4))) float fx4;

// ---- workspace layout (dword offsets) ----
#define W1D_OFF 0
#define W1S_OFF 448
#define WB1F_OFF 9216                 // f16 Wb frags layer1: 2048 dwords
#define WB2F_OFF 11264                // layer2: 2048 dwords
#define W2C_OFF 13312                 // combined f16 W2a frags (Wd||Ws): 4096 dwords
#define GCUR_OFF 17408                // bucket cursors [1024]
#define A_OFF   32768                 // packed f16: 32 dwords/node
#define B_OFF   (A_OFF + N64 / 2)
#define G1_OFF  (B_OFF + N64 / 2)     // layer-1 agg out, f16: 32 dwords/node
#define G2_OFF  (G1_OFF + N64 / 2)
#define P1_OFF  (G2_OFF + N64 / 2)    // int2[NB*CAP2] bucket staging

union FragH { unsigned u[4]; f16x8 f; };

static __device__ __forceinline__ unsigned pack_h2(float f0, float f1) {
    __half h0 = __float2half_rn(f0), h1 = __float2half_rn(f1);
    unsigned short u0 = *(unsigned short*)&h0, u1 = *(unsigned short*)&h1;
    return (unsigned)u0 | ((unsigned)u1 << 16);
}

// Prep: zero bucket cursors, precombine W1a, build f16 Wb frags + combined
// layer-2 node-MLP weight frags (Wd = top-bottom || Ws = bottom).
__global__ __launch_bounds__(256) void prep_all(
    const float* __restrict__ W1a, const float* __restrict__ W1b,
    const float* __restrict__ W2a, const float* __restrict__ W2b,
    float* __restrict__ ws, int* __restrict__ gcur)
{
    int t = blockIdx.x * 256 + threadIdx.x;
    if (t < 1024) gcur[t] = 0;
    if (t < 448) {
        float top = W1a[t], bot = W1a[448 + t];
        ws[W1D_OFF + t] = top - bot;
        ws[W1S_OFF + t] = bot;
    }
    if (t < 1024) {
        int layer = t >> 9;
        int r = t & 511;
        int ks = (r >> 8) & 1, nt = (r >> 6) & 3, lane = r & 63;
        const float* Wb = layer ? W2b : W1b;
        int* out = (int*)(ws + (layer ? WB2F_OFF : WB1F_OFF));
        int quad = lane >> 4, c = lane & 15, n = nt * 16 + c;
        unsigned dw[4];
#pragma unroll
        for (int d = 0; d < 4; ++d) {
            int k0 = quad * 8 + d * 2 + 32 * ks;
            dw[d] = pack_h2(Wb[k0 * 64 + n], Wb[(k0 + 1) * 64 + n]);
        }
        ((int4*)out)[r] = make_int4((int)dw[0], (int)dw[1], (int)dw[2], (int)dw[3]);
    }
    if (t >= 1024 && t < 2048) {
        int r = t - 1024;                       // ks*512 + nt*64 + lane
        int ks = (r >> 9) & 1, nt8 = (r >> 6) & 7, lane = r & 63;
        int quad = lane >> 4, c = lane & 15;
        int ncol = nt8 * 16 + c;                // 0..127
        int* out = (int*)(ws + W2C_OFF);
        unsigned dw[4];
#pragma unroll
        for (int d = 0; d < 4; ++d) {
            unsigned v[2];
#pragma unroll
            for (int e = 0; e < 2; ++e) {
                int k = quad * 8 + d * 2 + e + 32 * ks;
                float w = (ncol < 64)
                    ? (W2a[k * 64 + ncol] - W2a[(64 + k) * 64 + ncol])
                    : W2a[(64 + k) * 64 + (ncol - 64)];
                __half h = __float2half_rn(w);
                v[e] = *(unsigned short*)&h;
            }
            dw[d] = (v[1] << 16) | v[0];
        }
        ((int4*)out)[r] = make_int4((int)dw[0], (int)dw[1], (int)dw[2], (int)dw[3]);
    }
}

// Fused (1024-thread blocks): [0,MLP1_BLKS) = node-MLP1 (t>>8 selects output
// quarter, block covers 256 nodes); rest = bucket multisplit (dst>>7, NB=782).
__global__ __launch_bounds__(1024) void fused_mlp1_bucket(
    const float* __restrict__ x, const float* __restrict__ Wd,
    const float* __restrict__ Ws, const float* __restrict__ ba,
    unsigned* __restrict__ A16, unsigned* __restrict__ Bu,
    const int* __restrict__ src, const int* __restrict__ dst,
    int* __restrict__ gcur, int2* __restrict__ p1)
{
    __shared__ int cnt[NB];
    __shared__ int cur[NB];
    const int t = threadIdx.x;

    if (blockIdx.x < MLP1_BLKS) {
        const int q = t >> 8;
        const int i = blockIdx.x * 256 + (t & 255);
        if (i >= NN) return;
        float xv[7];
#pragma unroll
        for (int k = 0; k < 7; ++k) xv[k] = x[i * 7 + k];
        uint4* pa = (uint4*)(A16 + (size_t)i * 32 + q * 8);
        uint4* pb = (uint4*)(Bu + (size_t)i * 32 + q * 8);
        float acc[16];
#pragma unroll
        for (int c = 0; c < 16; ++c) acc[c] = ba[q * 16 + c];
#pragma unroll
        for (int k = 0; k < 7; ++k)
#pragma unroll
            for (int c = 0; c < 16; ++c)
                acc[c] = fmaf(xv[k], Wd[k * 64 + q * 16 + c], acc[c]);
        pa[0] = make_uint4(pack_h2(acc[0], acc[1]),  pack_h2(acc[2], acc[3]),
                           pack_h2(acc[4], acc[5]),  pack_h2(acc[6], acc[7]));
        pa[1] = make_uint4(pack_h2(acc[8], acc[9]),  pack_h2(acc[10], acc[11]),
                           pack_h2(acc[12], acc[13]), pack_h2(acc[14], acc[15]));
#pragma unroll
        for (int c = 0; c < 16; ++c) acc[c] = 0.0f;
#pragma unroll
        for (int k = 0; k < 7; ++k)
#pragma unroll
            for (int c = 0; c < 16; ++c)
                acc[c] = fmaf(xv[k], Ws[k * 64 + q * 16 + c], acc[c]);
        pb[0] = make_uint4(pack_h2(acc[0], acc[1]),  pack_h2(acc[2], acc[3]),
                           pack_h2(acc[4], acc[5]),  pack_h2(acc[6], acc[7]));
        pb[1] = make_uint4(pack_h2(acc[8], acc[9]),  pack_h2(acc[10], acc[11]),
                           pack_h2(acc[12], acc[13]), pack_h2(acc[14], acc[15]));
        return;
    }

    // ---- bucket role ----
    const int bb = blockIdx.x - MLP1_BLKS;
    const int e0 = (bb * 1024 + t) * 8;
    const bool ok = (e0 < NE);                   // NE % 8 == 0
    if (t < NB) cnt[t] = 0;
    int ss[8], dd[8], bk[8];
    if (ok) {
        int4 d0 = ((const int4*)(dst + e0))[0];
        int4 d1 = ((const int4*)(dst + e0))[1];
        int4 s0 = ((const int4*)(src + e0))[0];
        int4 s1 = ((const int4*)(src + e0))[1];
        dd[0]=d0.x; dd[1]=d0.y; dd[2]=d0.z; dd[3]=d0.w;
        dd[4]=d1.x; dd[5]=d1.y; dd[6]=d1.z; dd[7]=d1.w;
        ss[0]=s0.x; ss[1]=s0.y; ss[2]=s0.z; ss[3]=s0.w;
        ss[4]=s1.x; ss[5]=s1.y; ss[6]=s1.z; ss[7]=s1.w;
    }
    __syncthreads();
    if (ok) {
#pragma unroll
        for (int j = 0; j < 8; ++j) { bk[j] = dd[j] >> 7; atomicAdd(&cnt[bk[j]], 1); }
    }
    __syncthreads();
    if (t < NB) cur[t] = atomicAdd(&gcur[t], cnt[t]);   // reserve block ranges
    __syncthreads();
    if (ok) {
#pragma unroll
        for (int j = 0; j < 8; ++j) {
            int pos = atomicAdd(&cur[bk[j]], 1);
            p1[(size_t)bk[j] * CAP2 + pos] = make_int2(ss[j], dd[j]);
        }
    }
}

// Edge layer, bucket-resident: one block per 128-node bucket. fp32 agg in LDS
// (stride 66 vs bank conflicts), edges read unsorted from p1, wave = 32 edges,
// f16 MFMA, epilogue = direct ds_max_u32 (non-negative floats order as uints).
// Tail slots clamp to last edge: duplicates are idempotent under max.
// Writeout: 128 node rows as f16 once per block. No global atomics, no sort.
__global__ __launch_bounds__(256, 3) void edge_layer_bucket(
    const unsigned* __restrict__ A16, const unsigned* __restrict__ Bu,
    const int2* __restrict__ p1, const int* __restrict__ gcnt,
    const int* __restrict__ wbf, const float* __restrict__ bb,
    unsigned* __restrict__ G16)
{
    __shared__ unsigned agg[128 * 66];          // 33,792 B
    const int tid = threadIdx.x;
    const int wv = tid >> 6, lane = tid & 63;
    const int quad = lane >> 4, c15 = lane & 15;
    const int b = blockIdx.x;
    const int size = gcnt[b];
    const int szm1 = size - 1;
    const int2* bp = p1 + (size_t)b * CAP2;

    for (int i = tid; i < 128 * 66; i += 256) agg[i] = 0u;

    FragH wf[2][4];                              // persistent across iterations
#pragma unroll
    for (int ks = 0; ks < 2; ++ks)
#pragma unroll
        for (int nt = 0; nt < 4; ++nt) {
            int4 v = ((const int4*)wbf)[(ks * 4 + nt) * 64 + lane];
            wf[ks][nt].u[0] = (unsigned)v.x; wf[ks][nt].u[1] = (unsigned)v.y;
            wf[ks][nt].u[2] = (unsigned)v.z; wf[ks][nt].u[3] = (unsigned)v.w;
        }
    float bbv[4];
#pragma unroll
    for (int nt = 0; nt < 4; ++nt) bbv[nt] = bb[nt * 16 + c15];
    __syncthreads();

    const int niter = (size + 127) >> 7;
    for (int it = 0; it < niter; ++it) {
        const int base = it * 128 + wv * 32;
        int2 ed  = bp[min(base + (lane & 31), szm1)];
        int2 eb0 = bp[min(base + c15, szm1)];
        int2 eb1 = bp[min(base + 16 + c15, szm1)];
        const int dloc = ed.y & 127;             // dst - b*128

        const unsigned* pa0 = A16 + (size_t)eb0.y * 32 + quad * 4;
        const unsigned* pb0 = Bu  + (size_t)eb0.x * 32 + quad * 4;
        const unsigned* pa1 = A16 + (size_t)eb1.y * 32 + quad * 4;
        const unsigned* pb1 = Bu  + (size_t)eb1.x * 32 + quad * 4;

        uint4 ga[2][2], gb[2][2];
#pragma unroll
        for (int ks = 0; ks < 2; ++ks) {
            ga[0][ks] = ((const uint4*)(pa0 + ks * 16))[0];
            gb[0][ks] = ((const uint4*)(pb0 + ks * 16))[0];
            ga[1][ks] = ((const uint4*)(pa1 + ks * 16))[0];
            gb[1][ks] = ((const uint4*)(pb1 + ks * 16))[0];
        }

        FragH tf[2][2];
#pragma unroll
        for (int mt = 0; mt < 2; ++mt)
#pragma unroll
            for (int ks = 0; ks < 2; ++ks) {
                FragH ua, ub;
                ua.u[0] = ga[mt][ks].x; ua.u[1] = ga[mt][ks].y;
                ua.u[2] = ga[mt][ks].z; ua.u[3] = ga[mt][ks].w;
                ub.u[0] = gb[mt][ks].x; ub.u[1] = gb[mt][ks].y;
                ub.u[2] = gb[mt][ks].z; ub.u[3] = gb[mt][ks].w;
                f16x8 s = ua.f + ub.f;
                tf[mt][ks].f = __builtin_elementwise_max(s, (f16x8)(_Float16)0.0f);
            }

        fx4 acc[2][4];
#pragma unroll
        for (int mt = 0; mt < 2; ++mt)
#pragma unroll
            for (int nt = 0; nt < 4; ++nt)
                acc[mt][nt] = (fx4){0.f, 0.f, 0.f, 0.f};
#pragma unroll
        for (int ks = 0; ks < 2; ++ks)
#pragma unroll
            for (int mt = 0; mt < 2; ++mt)
#pragma unroll
                for (int nt = 0; nt < 4; ++nt)
                    acc[mt][nt] = __builtin_amdgcn_mfma_f32_16x16x32_f16(
                        tf[mt][ks].f, wf[ks][nt].f, acc[mt][nt], 0, 0, 0);

        // epilogue: per value (edge 16mt+4q+r, ch 16nt+c15) -> ds_max
#pragma unroll
        for (int mt = 0; mt < 2; ++mt)
#pragma unroll
            for (int r = 0; r < 4; ++r) {
                int dl = __builtin_amdgcn_ds_bpermute(
                    (16 * mt + 4 * quad + r) * 4, dloc);
                int abase = dl * 66 + c15;
#pragma unroll
                for (int nt = 0; nt < 4; ++nt) {
                    float h = fmaxf(acc[mt][nt][r] + bbv[nt], 0.f);
                    atomicMax(&agg[abase + nt * 16], __float_as_uint(h));
                }
            }
    }
    __syncthreads();

    // writeout: 2 threads per node, 32 ch each, f16 packed
    const int nl = tid >> 1, ch32 = (tid & 1) * 32;
    const int node = b * 128 + nl;
    if (node < NN) {
        unsigned* out = G16 + (size_t)node * 32 + (tid & 1) * 16;
#pragma unroll
        for (int j = 0; j < 16; ++j) {
            float f0 = __uint_as_float(agg[nl * 66 + ch32 + 2 * j]);
            float f1 = __uint_as_float(agg[nl * 66 + ch32 + 2 * j + 1]);
            out[j] = pack_h2(f0, f1);
        }
    }
}

// Node MLP layer 2 as MFMA GEMM over f16 g: [NN x 64] @ [64 x 128] (Wd || Ws).
// A-frags are direct uint4 loads of the f16 rows (no converts at all).
__global__ __launch_bounds__(256, 3) void node_mlp2_mfma(
    const unsigned* __restrict__ g16, const int* __restrict__ wcf,
    const float* __restrict__ ba2,
    unsigned* __restrict__ A16, unsigned* __restrict__ Bu)
{
    const int tid = threadIdx.x;
    const int wv = tid >> 6, lane = tid & 63;
    const int quad = lane >> 4, c15 = lane & 15;
    const int nbase = (blockIdx.x * 4 + wv) * 32;
    if (nbase >= NN) return;                     // 3125 full waves exactly

    FragH tf[2][2];
#pragma unroll
    for (int mt = 0; mt < 2; ++mt) {
        const unsigned* pr = g16 + (size_t)(nbase + mt * 16 + c15) * 32 + quad * 4;
#pragma unroll
        for (int ks = 0; ks < 2; ++ks) {
            uint4 v = ((const uint4*)(pr + ks * 16))[0];
            tf[mt][ks].u[0] = v.x; tf[mt][ks].u[1] = v.y;
            tf[mt][ks].u[2] = v.z; tf[mt][ks].u[3] = v.w;
        }
    }

    fx4 acc[2][8];
#pragma unroll
    for (int mt = 0; mt < 2; ++mt)
#pragma unroll
        for (int nt = 0; nt < 8; ++nt)
            acc[mt][nt] = (fx4){0.f, 0.f, 0.f, 0.f};

#pragma unroll
    for (int ks = 0; ks < 2; ++ks) {
        FragH wf[8];
#pragma unroll
        for (int nt = 0; nt < 8; ++nt) {
            int4 v = ((const int4*)wcf)[(ks * 8 + nt) * 64 + lane];
            wf[nt].u[0] = (unsigned)v.x; wf[nt].u[1] = (unsigned)v.y;
            wf[nt].u[2] = (unsigned)v.z; wf[nt].u[3] = (unsigned)v.w;
        }
#pragma unroll
        for (int mt = 0; mt < 2; ++mt)
#pragma unroll
            for (int nt = 0; nt < 8; ++nt)
                acc[mt][nt] = __builtin_amdgcn_mfma_f32_16x16x32_f16(
                    tf[mt][ks].f, wf[nt].f, acc[mt][nt], 0, 0, 0);
    }

    __half* Ah = (__half*)A16;
    __half* Bh = (__half*)Bu;
#pragma unroll
    for (int nt = 0; nt < 8; ++nt) {
        float bbv = (nt < 4) ? ba2[nt * 16 + c15] : 0.f;
        __half* out = (nt < 4) ? Ah : Bh;
        int ch = (nt & 3) * 16 + c15;
#pragma unroll
        for (int mt = 0; mt < 2; ++mt)
#pragma unroll
            for (int r = 0; r < 4; ++r) {
                int node = nbase + mt * 16 + quad * 4 + r;
                out[(size_t)node * 64 + ch] = __float2half_rn(acc[mt][nt][r] + bbv);
            }
    }
}

// out[i] = h2[i,:] @ Wl + bl, h2 stored f16
__global__ __launch_bounds__(256) void final_linear(
    const unsigned* __restrict__ g2, const float* __restrict__ Wl,
    const float* __restrict__ bl, float* __restrict__ out)
{
    int i = blockIdx.x * 256 + threadIdx.x;
    if (i >= NN) return;
    const uint4* row = (const uint4*)(g2 + (size_t)i * 32);
    float acc = bl[0];
#pragma unroll
    for (int q = 0; q < 8; ++q) {
        uint4 v = row[q];
        unsigned u[4] = { v.x, v.y, v.z, v.w };
#pragma unroll
        for (int d = 0; d < 4; ++d) {
            float2 f = __half22float2(*(const __half2*)&u[d]);
            acc = fmaf(f.x, Wl[q * 8 + d * 2], acc);
            acc = fmaf(f.y, Wl[q * 8 + d * 2 + 1], acc);
        }
    }
    out[i] = acc;
}

extern "C" void kernel_launch(void* const* d_in, const int* in_sizes, int n_in,
                              void* d_out, int out_size, void* d_ws, size_t ws_size,
                              hipStream_t stream)
{
    const float* x   = (const float*)d_in[0];
    const int*   ei  = (const int*)d_in[1];
    const float* W1a = (const float*)d_in[2];
    const float* b1a = (const float*)d_in[3];
    const float* W1b = (const float*)d_in[4];
    const float* b1b = (const float*)d_in[5];
    const float* W2a = (const float*)d_in[6];
    const float* b2a = (const float*)d_in[7];
    const float* W2b = (const float*)d_in[8];
    const float* b2b = (const float*)d_in[9];
    const float* Wl  = (const float*)d_in[10];
    const float* bl  = (const float*)d_in[11];

    const int* src = ei;
    const int* dst = ei + NE;

    float* ws = (float*)d_ws;
    unsigned* A16 = (unsigned*)(ws + A_OFF);
    unsigned* Bu  = (unsigned*)(ws + B_OFF);
    unsigned* G1  = (unsigned*)(ws + G1_OFF);
    unsigned* G2  = (unsigned*)(ws + G2_OFF);
    int*  gcur  = (int*)(ws + GCUR_OFF);
    int2* p1    = (int2*)(ws + P1_OFF);

    prep_all<<<16, 256, 0, stream>>>(W1a, W1b, W2a, W2b, ws, gcur);

    fused_mlp1_bucket<<<MLP1_BLKS + BKT_BLKS, 1024, 0, stream>>>(
        x, ws + W1D_OFF, ws + W1S_OFF, b1a, A16, Bu, src, dst, gcur, p1);

    edge_layer_bucket<<<NB, 256, 0, stream>>>(A16, Bu, p1, gcur,
                                              (const int*)(ws + WB1F_OFF), b1b, G1);

    node_mlp2_mfma<<<782, 256, 0, stream>>>(G1, (const int*)(ws + W2C_OFF),
                                            b2a, A16, Bu);

    edge_layer_bucket<<<NB, 256, 0, stream>>>(A16, Bu, p1, gcur,
                                              (const int*)(ws + WB2F_OFF), b2b, G2);

    final_linear<<<391, 256, 0, stream>>>(G2, Wl, bl, (float*)d_out);
}

// Round 15
// 262.624 us; speedup vs baseline: 1.7194x; 1.0548x over previous
//
#include <hip/hip_runtime.h>
#include <hip/hip_fp16.h>

#define NN 100000
#define NE 1600000
#define N64 (NN * 64)
#define NB 1563                       // buckets = dst>>6 (ceil(100000/64))
#define CAP2 1280                     // bucket capacity (mean ~1024, +8 sigma)
#define MLP1_BLKS 391                 // mlp1 role: block covers 256 nodes x 4 quarters
#define BKT_BLKS 196                  // 196 * 1024 * 8 >= NE

typedef __attribute__((ext_vector_type(8))) _Float16 f16x8;
typedef __attribute__((ext_vector_type(4))) float fx4;

// ---- workspace layout (dword offsets) ----
#define W1D_OFF 0
#define W1S_OFF 448
#define WB1F_OFF 9216                 // f16 Wb frags layer1: 2048 dwords
#define WB2F_OFF 11264                // layer2: 2048 dwords
#define W2C_OFF 13312                 // combined f16 W2a frags (Wd||Ws): 4096 dwords
#define GCUR_OFF 17408                // bucket cursors [NB]
#define A_OFF   32768                 // packed f16: 32 dwords/node
#define B_OFF   (A_OFF + N64 / 2)
#define G1_OFF  (B_OFF + N64 / 2)     // layer-1 agg out, f16: 32 dwords/node
#define G2_OFF  (G1_OFF + N64 / 2)
#define P1_OFF  (G2_OFF + N64 / 2)    // int2[NB*CAP2] bucket staging

union FragH { unsigned u[4]; f16x8 f; };

static __device__ __forceinline__ unsigned pack_h2(float f0, float f1) {
    __half h0 = __float2half_rn(f0), h1 = __float2half_rn(f1);
    unsigned short u0 = *(unsigned short*)&h0, u1 = *(unsigned short*)&h1;
    return (unsigned)u0 | ((unsigned)u1 << 16);
}

// Prep: zero bucket cursors, precombine W1a, build f16 Wb frags + combined
// layer-2 node-MLP weight frags (Wd = top-bottom || Ws = bottom).
__global__ __launch_bounds__(256) void prep_all(
    const float* __restrict__ W1a, const float* __restrict__ W1b,
    const float* __restrict__ W2a, const float* __restrict__ W2b,
    float* __restrict__ ws, int* __restrict__ gcur)
{
    int t = blockIdx.x * 256 + threadIdx.x;
    if (t < NB) gcur[t] = 0;
    if (t < 448) {
        float top = W1a[t], bot = W1a[448 + t];
        ws[W1D_OFF + t] = top - bot;
        ws[W1S_OFF + t] = bot;
    }
    if (t < 1024) {
        int layer = t >> 9;
        int r = t & 511;
        int ks = (r >> 8) & 1, nt = (r >> 6) & 3, lane = r & 63;
        const float* Wb = layer ? W2b : W1b;
        int* out = (int*)(ws + (layer ? WB2F_OFF : WB1F_OFF));
        int quad = lane >> 4, c = lane & 15, n = nt * 16 + c;
        unsigned dw[4];
#pragma unroll
        for (int d = 0; d < 4; ++d) {
            int k0 = quad * 8 + d * 2 + 32 * ks;
            dw[d] = pack_h2(Wb[k0 * 64 + n], Wb[(k0 + 1) * 64 + n]);
        }
        ((int4*)out)[r] = make_int4((int)dw[0], (int)dw[1], (int)dw[2], (int)dw[3]);
    }
    if (t >= 1024 && t < 2048) {
        int r = t - 1024;                       // ks*512 + nt*64 + lane
        int ks = (r >> 9) & 1, nt8 = (r >> 6) & 7, lane = r & 63;
        int quad = lane >> 4, c = lane & 15;
        int ncol = nt8 * 16 + c;                // 0..127
        int* out = (int*)(ws + W2C_OFF);
        unsigned dw[4];
#pragma unroll
        for (int d = 0; d < 4; ++d) {
            unsigned v[2];
#pragma unroll
            for (int e = 0; e < 2; ++e) {
                int k = quad * 8 + d * 2 + e + 32 * ks;
                float w = (ncol < 64)
                    ? (W2a[k * 64 + ncol] - W2a[(64 + k) * 64 + ncol])
                    : W2a[(64 + k) * 64 + (ncol - 64)];
                __half h = __float2half_rn(w);
                v[e] = *(unsigned short*)&h;
            }
            dw[d] = (v[1] << 16) | v[0];
        }
        ((int4*)out)[r] = make_int4((int)dw[0], (int)dw[1], (int)dw[2], (int)dw[3]);
    }
}

// Fused (1024-thread blocks): [0,MLP1_BLKS) = node-MLP1 (t>>8 selects output
// quarter, block covers 256 nodes); rest = bucket multisplit (dst>>6, NB=1563).
__global__ __launch_bounds__(1024) void fused_mlp1_bucket(
    const float* __restrict__ x, const float* __restrict__ Wd,
    const float* __restrict__ Ws, const float* __restrict__ ba,
    unsigned* __restrict__ A16, unsigned* __restrict__ Bu,
    const int* __restrict__ src, const int* __restrict__ dst,
    int* __restrict__ gcur, int2* __restrict__ p1)
{
    __shared__ int cnt[NB];
    __shared__ int cur[NB];
    const int t = threadIdx.x;

    if (blockIdx.x < MLP1_BLKS) {
        const int q = t >> 8;
        const int i = blockIdx.x * 256 + (t & 255);
        if (i >= NN) return;
        float xv[7];
#pragma unroll
        for (int k = 0; k < 7; ++k) xv[k] = x[i * 7 + k];
        uint4* pa = (uint4*)(A16 + (size_t)i * 32 + q * 8);
        uint4* pb = (uint4*)(Bu + (size_t)i * 32 + q * 8);
        float acc[16];
#pragma unroll
        for (int c = 0; c < 16; ++c) acc[c] = ba[q * 16 + c];
#pragma unroll
        for (int k = 0; k < 7; ++k)
#pragma unroll
            for (int c = 0; c < 16; ++c)
                acc[c] = fmaf(xv[k], Wd[k * 64 + q * 16 + c], acc[c]);
        pa[0] = make_uint4(pack_h2(acc[0], acc[1]),  pack_h2(acc[2], acc[3]),
                           pack_h2(acc[4], acc[5]),  pack_h2(acc[6], acc[7]));
        pa[1] = make_uint4(pack_h2(acc[8], acc[9]),  pack_h2(acc[10], acc[11]),
                           pack_h2(acc[12], acc[13]), pack_h2(acc[14], acc[15]));
#pragma unroll
        for (int c = 0; c < 16; ++c) acc[c] = 0.0f;
#pragma unroll
        for (int k = 0; k < 7; ++k)
#pragma unroll
            for (int c = 0; c < 16; ++c)
                acc[c] = fmaf(xv[k], Ws[k * 64 + q * 16 + c], acc[c]);
        pb[0] = make_uint4(pack_h2(acc[0], acc[1]),  pack_h2(acc[2], acc[3]),
                           pack_h2(acc[4], acc[5]),  pack_h2(acc[6], acc[7]));
        pb[1] = make_uint4(pack_h2(acc[8], acc[9]),  pack_h2(acc[10], acc[11]),
                           pack_h2(acc[12], acc[13]), pack_h2(acc[14], acc[15]));
        return;
    }

    // ---- bucket role ----
    const int bb = blockIdx.x - MLP1_BLKS;
    const int e0 = (bb * 1024 + t) * 8;
    const bool ok = (e0 < NE);                   // NE % 8 == 0
    for (int i = t; i < NB; i += 1024) cnt[i] = 0;
    int ss[8], dd[8], bk[8];
    if (ok) {
        int4 d0 = ((const int4*)(dst + e0))[0];
        int4 d1 = ((const int4*)(dst + e0))[1];
        int4 s0 = ((const int4*)(src + e0))[0];
        int4 s1 = ((const int4*)(src + e0))[1];
        dd[0]=d0.x; dd[1]=d0.y; dd[2]=d0.z; dd[3]=d0.w;
        dd[4]=d1.x; dd[5]=d1.y; dd[6]=d1.z; dd[7]=d1.w;
        ss[0]=s0.x; ss[1]=s0.y; ss[2]=s0.z; ss[3]=s0.w;
        ss[4]=s1.x; ss[5]=s1.y; ss[6]=s1.z; ss[7]=s1.w;
    }
    __syncthreads();
    if (ok) {
#pragma unroll
        for (int j = 0; j < 8; ++j) { bk[j] = dd[j] >> 6; atomicAdd(&cnt[bk[j]], 1); }
    }
    __syncthreads();
    for (int i = t; i < NB; i += 1024)
        cur[i] = atomicAdd(&gcur[i], cnt[i]);    // reserve block ranges
    __syncthreads();
    if (ok) {
#pragma unroll
        for (int j = 0; j < 8; ++j) {
            int pos = atomicAdd(&cur[bk[j]], 1);
            p1[(size_t)bk[j] * CAP2 + pos] = make_int2(ss[j], dd[j]);
        }
    }
}

// Edge layer, bucket-resident: one block per 64-node bucket. fp32 agg in LDS
// (stride 66), edges read unsorted from p1, wave = 32 edges, f16 MFMA,
// epilogue = ds atomicMax (non-negative floats order as uints). Index loads
// software-pipelined one iteration ahead. Tail slots clamp to last edge
// (duplicates idempotent under max). Writeout: 64 f16 node rows per block.
__global__ __launch_bounds__(256, 4) void edge_layer_bucket(
    const unsigned* __restrict__ A16, const unsigned* __restrict__ Bu,
    const int2* __restrict__ p1, const int* __restrict__ gcnt,
    const int* __restrict__ wbf, const float* __restrict__ bb,
    unsigned* __restrict__ G16)
{
    __shared__ unsigned agg[64 * 66];            // 16,896 B
    const int tid = threadIdx.x;
    const int wv = tid >> 6, lane = tid & 63;
    const int quad = lane >> 4, c15 = lane & 15;
    const int b = blockIdx.x;
    const int size = gcnt[b];
    const int szm1 = size - 1;
    const int2* bp = p1 + (size_t)b * CAP2;

    for (int i = tid; i < 64 * 66; i += 256) agg[i] = 0u;

    FragH wf[2][4];                              // persistent across iterations
#pragma unroll
    for (int ks = 0; ks < 2; ++ks)
#pragma unroll
        for (int nt = 0; nt < 4; ++nt) {
            int4 v = ((const int4*)wbf)[(ks * 4 + nt) * 64 + lane];
            wf[ks][nt].u[0] = (unsigned)v.x; wf[ks][nt].u[1] = (unsigned)v.y;
            wf[ks][nt].u[2] = (unsigned)v.z; wf[ks][nt].u[3] = (unsigned)v.w;
        }
    float bbv[4];
#pragma unroll
    for (int nt = 0; nt < 4; ++nt) bbv[nt] = bb[nt * 16 + c15];
    __syncthreads();

    const int niter = (size + 127) >> 7;
    // preload iteration-0 indices
    int2 ed = make_int2(0, 0), eb0 = ed, eb1 = ed;
    if (niter > 0) {
        int base = wv * 32;
        ed  = bp[min(base + (lane & 31), szm1)];
        eb0 = bp[min(base + c15, szm1)];
        eb1 = bp[min(base + 16 + c15, szm1)];
    }

    for (int it = 0; it < niter; ++it) {
        const int2 ced = ed, ceb0 = eb0, ceb1 = eb1;
        if (it + 1 < niter) {                    // prefetch next indices
            int nb2 = (it + 1) * 128 + wv * 32;
            ed  = bp[min(nb2 + (lane & 31), szm1)];
            eb0 = bp[min(nb2 + c15, szm1)];
            eb1 = bp[min(nb2 + 16 + c15, szm1)];
        }
        const int dloc = ced.y & 63;             // dst - b*64

        const unsigned* pa0 = A16 + (size_t)ceb0.y * 32 + quad * 4;
        const unsigned* pb0 = Bu  + (size_t)ceb0.x * 32 + quad * 4;
        const unsigned* pa1 = A16 + (size_t)ceb1.y * 32 + quad * 4;
        const unsigned* pb1 = Bu  + (size_t)ceb1.x * 32 + quad * 4;

        uint4 ga[2][2], gb[2][2];
#pragma unroll
        for (int ks = 0; ks < 2; ++ks) {
            ga[0][ks] = ((const uint4*)(pa0 + ks * 16))[0];
            gb[0][ks] = ((const uint4*)(pb0 + ks * 16))[0];
            ga[1][ks] = ((const uint4*)(pa1 + ks * 16))[0];
            gb[1][ks] = ((const uint4*)(pb1 + ks * 16))[0];
        }

        FragH tf[2][2];
#pragma unroll
        for (int mt = 0; mt < 2; ++mt)
#pragma unroll
            for (int ks = 0; ks < 2; ++ks) {
                FragH ua, ub;
                ua.u[0] = ga[mt][ks].x; ua.u[1] = ga[mt][ks].y;
                ua.u[2] = ga[mt][ks].z; ua.u[3] = ga[mt][ks].w;
                ub.u[0] = gb[mt][ks].x; ub.u[1] = gb[mt][ks].y;
                ub.u[2] = gb[mt][ks].z; ub.u[3] = gb[mt][ks].w;
                f16x8 s = ua.f + ub.f;
                tf[mt][ks].f = __builtin_elementwise_max(s, (f16x8)(_Float16)0.0f);
            }

        fx4 acc[2][4];
#pragma unroll
        for (int mt = 0; mt < 2; ++mt)
#pragma unroll
            for (int nt = 0; nt < 4; ++nt)
                acc[mt][nt] = (fx4){0.f, 0.f, 0.f, 0.f};
#pragma unroll
        for (int ks = 0; ks < 2; ++ks)
#pragma unroll
            for (int mt = 0; mt < 2; ++mt)
#pragma unroll
                for (int nt = 0; nt < 4; ++nt)
                    acc[mt][nt] = __builtin_amdgcn_mfma_f32_16x16x32_f16(
                        tf[mt][ks].f, wf[ks][nt].f, acc[mt][nt], 0, 0, 0);

        // epilogue: per value (edge 16mt+4q+r, ch 16nt+c15) -> ds atomic max
#pragma unroll
        for (int mt = 0; mt < 2; ++mt)
#pragma unroll
            for (int r = 0; r < 4; ++r) {
                int dl = __builtin_amdgcn_ds_bpermute(
                    (16 * mt + 4 * quad + r) * 4, dloc);
                int abase = dl * 66 + c15;
#pragma unroll
                for (int nt = 0; nt < 4; ++nt) {
                    float h = fmaxf(acc[mt][nt][r] + bbv[nt], 0.f);
                    atomicMax(&agg[abase + nt * 16], __float_as_uint(h));
                }
            }
    }
    __syncthreads();

    // writeout: 4 threads per node, 16 ch each, f16 packed
    const int nl = tid >> 2, part = tid & 3;
    const int node = b * 64 + nl;
    if (node < NN) {
        unsigned* out = G16 + (size_t)node * 32 + part * 8;
#pragma unroll
        for (int j = 0; j < 8; ++j) {
            float f0 = __uint_as_float(agg[nl * 66 + part * 16 + 2 * j]);
            float f1 = __uint_as_float(agg[nl * 66 + part * 16 + 2 * j + 1]);
            out[j] = pack_h2(f0, f1);
        }
    }
}

// Node MLP layer 2 as MFMA GEMM over f16 g: [NN x 64] @ [64 x 128] (Wd || Ws).
__global__ __launch_bounds__(256, 3) void node_mlp2_mfma(
    const unsigned* __restrict__ g16, const int* __restrict__ wcf,
    const float* __restrict__ ba2,
    unsigned* __restrict__ A16, unsigned* __restrict__ Bu)
{
    const int tid = threadIdx.x;
    const int wv = tid >> 6, lane = tid & 63;
    const int quad = lane >> 4, c15 = lane & 15;
    const int nbase = (blockIdx.x * 4 + wv) * 32;
    if (nbase >= NN) return;                     // 3125 full waves exactly

    FragH tf[2][2];
#pragma unroll
    for (int mt = 0; mt < 2; ++mt) {
        const unsigned* pr = g16 + (size_t)(nbase + mt * 16 + c15) * 32 + quad * 4;
#pragma unroll
        for (int ks = 0; ks < 2; ++ks) {
            uint4 v = ((const uint4*)(pr + ks * 16))[0];
            tf[mt][ks].u[0] = v.x; tf[mt][ks].u[1] = v.y;
            tf[mt][ks].u[2] = v.z; tf[mt][ks].u[3] = v.w;
        }
    }

    fx4 acc[2][8];
#pragma unroll
    for (int mt = 0; mt < 2; ++mt)
#pragma unroll
        for (int nt = 0; nt < 8; ++nt)
            acc[mt][nt] = (fx4){0.f, 0.f, 0.f, 0.f};

#pragma unroll
    for (int ks = 0; ks < 2; ++ks) {
        FragH wf[8];
#pragma unroll
        for (int nt = 0; nt < 8; ++nt) {
            int4 v = ((const int4*)wcf)[(ks * 8 + nt) * 64 + lane];
            wf[nt].u[0] = (unsigned)v.x; wf[nt].u[1] = (unsigned)v.y;
            wf[nt].u[2] = (unsigned)v.z; wf[nt].u[3] = (unsigned)v.w;
        }
#pragma unroll
        for (int mt = 0; mt < 2; ++mt)
#pragma unroll
            for (int nt = 0; nt < 8; ++nt)
                acc[mt][nt] = __builtin_amdgcn_mfma_f32_16x16x32_f16(
                    tf[mt][ks].f, wf[nt].f, acc[mt][nt], 0, 0, 0);
    }

    __half* Ah = (__half*)A16;
    __half* Bh = (__half*)Bu;
#pragma unroll
    for (int nt = 0; nt < 8; ++nt) {
        float bbv = (nt < 4) ? ba2[nt * 16 + c15] : 0.f;
        __half* out = (nt < 4) ? Ah : Bh;
        int ch = (nt & 3) * 16 + c15;
#pragma unroll
        for (int mt = 0; mt < 2; ++mt)
#pragma unroll
            for (int r = 0; r < 4; ++r) {
                int node = nbase + mt * 16 + quad * 4 + r;
                out[(size_t)node * 64 + ch] = __float2half_rn(acc[mt][nt][r] + bbv);
            }
    }
}

// out[i] = h2[i,:] @ Wl + bl, h2 stored f16
__global__ __launch_bounds__(256) void final_linear(
    const unsigned* __restrict__ g2, const float* __restrict__ Wl,
    const float* __restrict__ bl, float* __restrict__ out)
{
    int i = blockIdx.x * 256 + threadIdx.x;
    if (i >= NN) return;
    const uint4* row = (const uint4*)(g2 + (size_t)i * 32);
    float acc = bl[0];
#pragma unroll
    for (int q = 0; q < 8; ++q) {
        uint4 v = row[q];
        unsigned u[4] = { v.x, v.y, v.z, v.w };
#pragma unroll
        for (int d = 0; d < 4; ++d) {
            float2 f = __half22float2(*(const __half2*)&u[d]);
            acc = fmaf(f.x, Wl[q * 8 + d * 2], acc);
            acc = fmaf(f.y, Wl[q * 8 + d * 2 + 1], acc);
        }
    }
    out[i] = acc;
}

extern "C" void kernel_launch(void* const* d_in, const int* in_sizes, int n_in,
                              void* d_out, int out_size, void* d_ws, size_t ws_size,
                              hipStream_t stream)
{
    const float* x   = (const float*)d_in[0];
    const int*   ei  = (const int*)d_in[1];
    const float* W1a = (const float*)d_in[2];
    const float* b1a = (const float*)d_in[3];
    const float* W1b = (const float*)d_in[4];
    const float* b1b = (const float*)d_in[5];
    const float* W2a = (const float*)d_in[6];
    const float* b2a = (const float*)d_in[7];
    const float* W2b = (const float*)d_in[8];
    const float* b2b = (const float*)d_in[9];
    const float* Wl  = (const float*)d_in[10];
    const float* bl  = (const float*)d_in[11];

    const int* src = ei;
    const int* dst = ei + NE;

    float* ws = (float*)d_ws;
    unsigned* A16 = (unsigned*)(ws + A_OFF);
    unsigned* Bu  = (unsigned*)(ws + B_OFF);
    unsigned* G1  = (unsigned*)(ws + G1_OFF);
    unsigned* G2  = (unsigned*)(ws + G2_OFF);
    int*  gcur  = (int*)(ws + GCUR_OFF);
    int2* p1    = (int2*)(ws + P1_OFF);

    prep_all<<<16, 256, 0, stream>>>(W1a, W1b, W2a, W2b, ws, gcur);

    fused_mlp1_bucket<<<MLP1_BLKS + BKT_BLKS, 1024, 0, stream>>>(
        x, ws + W1D_OFF, ws + W1S_OFF, b1a, A16, Bu, src, dst, gcur, p1);

    edge_layer_bucket<<<NB, 256, 0, stream>>>(A16, Bu, p1, gcur,
                                              (const int*)(ws + WB1F_OFF), b1b, G1);

    node_mlp2_mfma<<<782, 256, 0, stream>>>(G1, (const int*)(ws + W2C_OFF),
                                            b2a, A16, Bu);

    edge_layer_bucket<<<NB, 256, 0, stream>>>(A16, Bu, p1, gcur,
                                              (const int*)(ws + WB2F_OFF), b2b, G2);

    final_linear<<<391, 256, 0, stream>>>(G2, Wl, bl, (float*)d_out);
}